// Round 7
// baseline (1932.693 us; speedup 1.0000x reference)
//
#include <hip/hip_runtime.h>
#include <hip/hip_fp16.h>
#include <cstddef>

#define NN 100000
#define EE 3200000
#define EPSB 1e-5f
#define NB 391      // buckets = ceil(NN/256)
#define BCAP 10240  // per-bucket edge capacity
#define BNBLK 512   // BN partial blocks (atomic-free tree reduce)
#define NBLK128 782 // ceil(NN/128) node-blocks for slice agg

typedef _Float16 half8 __attribute__((ext_vector_type(8)));
typedef float floatx4 __attribute__((ext_vector_type(4)));
typedef float f32x4v __attribute__((ext_vector_type(4)));
typedef unsigned u32x4v __attribute__((ext_vector_type(4)));

// nontemporal store helpers (builtin rejects HIP_vector_type; go via ext_vector)
__device__ __forceinline__ void nt_store_f4(const float4& v, float4* p) {
    f32x4v t = {v.x, v.y, v.z, v.w};
    __builtin_nontemporal_store(t, (f32x4v*)p);
}
__device__ __forceinline__ void nt_store_u4(const uint4& v, uint4* p) {
    u32x4v t = {v.x, v.y, v.z, v.w};
    __builtin_nontemporal_store(t, (u32x4v*)p);
}

// ---------------------------------------------------------------- CSR build
// packed record: src (17 bits) | dst&255 (8 bits) << 17

__global__ __launch_bounds__(256) void k_bscat(const int* __restrict__ src,
                                               const int* __restrict__ dst,
                                               int* __restrict__ bcur,
                                               unsigned* __restrict__ barr) {
    __shared__ int hist[NB];
    __shared__ int base[NB];
    int tid = threadIdx.x;
    for (int b = tid; b < NB; b += 256) hist[b] = 0;
    __syncthreads();
    int e0 = blockIdx.x * 4096;
    int d[16], s[16];
    #pragma unroll
    for (int j = 0; j < 16; j++) {
        int e = e0 + j * 256 + tid;
        if (e < EE) {
            d[j] = dst[e];
            s[j] = src[e];
            atomicAdd(&hist[d[j] >> 8], 1);
        } else d[j] = -1;
    }
    __syncthreads();
    for (int b = tid; b < NB; b += 256) {
        int c = hist[b];
        base[b] = (c > 0) ? atomicAdd(&bcur[b], c) : 0;
        hist[b] = 0;
    }
    __syncthreads();
    #pragma unroll
    for (int j = 0; j < 16; j++) {
        if (d[j] >= 0) {
            int b = d[j] >> 8;
            int r = atomicAdd(&hist[b], 1);
            barr[(size_t)b * BCAP + base[b] + r] =
                (unsigned)s[j] | ((unsigned)(d[j] & 255) << 17);
        }
    }
}

__global__ __launch_bounds__(1024) void k_bdeg(const int* __restrict__ bcur,
                                               const unsigned* __restrict__ barr,
                                               int* __restrict__ degcnt,
                                               float* __restrict__ dis) {
    __shared__ int h[256];
    int b = blockIdx.x;
    if (threadIdx.x < 256) h[threadIdx.x] = 0;
    __syncthreads();
    int cnt = bcur[b];
    const unsigned* p = barr + (size_t)b * BCAP;
    for (int t = threadIdx.x; t < cnt; t += 1024)
        atomicAdd(&h[(p[t] >> 17) & 255], 1);
    __syncthreads();
    if (threadIdx.x < 256) {
        int node = (b << 8) + threadIdx.x;
        if (node < NN) {
            int dg = h[threadIdx.x];
            degcnt[node] = dg;
            dis[node] = rsqrtf((float)dg + 1.0f);
        }
    }
}

__global__ __launch_bounds__(1024) void k_place(const int* __restrict__ bcur,
                                                const unsigned* __restrict__ barr,
                                                const int* __restrict__ rowptr,
                                                int* __restrict__ col) {
    __shared__ int cur[256];
    int b = blockIdx.x;
    if (threadIdx.x < 256) {
        int node = (b << 8) + threadIdx.x;
        cur[threadIdx.x] = (node < NN) ? rowptr[node] : 0;
    }
    __syncthreads();
    int cnt = bcur[b];
    const unsigned* p = barr + (size_t)b * BCAP;
    for (int t = threadIdx.x; t < cnt; t += 1024) {
        unsigned e = p[t];
        int pos = atomicAdd(&cur[(e >> 17) & 255], 1);
        col[pos] = (int)(e & 0x1FFFFu);
    }
}

__global__ void k_scan_block(const int* __restrict__ in, int* __restrict__ out,
                             int* __restrict__ blksum, int n) {
    __shared__ int s[1024];
    int i = blockIdx.x * 1024 + threadIdx.x;
    int v = (i < n) ? in[i] : 0;
    s[threadIdx.x] = v;
    __syncthreads();
    for (int off = 1; off < 1024; off <<= 1) {
        int t = (threadIdx.x >= off) ? s[threadIdx.x - off] : 0;
        __syncthreads();
        s[threadIdx.x] += t;
        __syncthreads();
    }
    if (i < n) out[i] = s[threadIdx.x] - v;  // exclusive
    if (threadIdx.x == 1023) blksum[blockIdx.x] = s[1023];
}

__global__ void k_scan_top(int* __restrict__ blksum, int nb) {
    if (threadIdx.x == 0) {
        int acc = 0;
        for (int b = 0; b < nb; b++) { int v = blksum[b]; blksum[b] = acc; acc += v; }
    }
}

__global__ void k_scan_add(int* __restrict__ out, const int* __restrict__ blksum, int n) {
    int i = blockIdx.x * 1024 + threadIdx.x;
    if (i < n) out[i] += blksum[blockIdx.x];
}

// ---------------------------------------------------------------- casts / packing

__global__ void k_f2h(const float4* __restrict__ in, uint2* __restrict__ out, int n4) {
    int t = blockIdx.x * blockDim.x + threadIdx.x;
    if (t >= n4) return;
    float4 v = in[t];
    union { __half2 h; unsigned u; } a, b;
    a.h = __floats2half2_rn(v.x, v.y);
    b.h = __floats2half2_rn(v.z, v.w);
    out[t] = make_uint2(a.u, b.u);
}

__global__ void k_wpack_all(const float* __restrict__ W0, const float* __restrict__ W1,
                            const float* __restrict__ W2, const float* __restrict__ W3,
                            const float* __restrict__ W4, __half* __restrict__ Wp) {
    const int offs[6] = {0, 16384, 49152, 81920, 90112, 92160};
    const int Ks[5] = {128, 128, 256, 128, 64};
    const int Ns[5] = {128, 256, 128, 64, 32};
    const float* Ws[5] = {W0, W1, W2, W3, W4};
    int t = blockIdx.x * blockDim.x + threadIdx.x;
    if (t >= 92160) return;
    int l = 0;
    while (t >= offs[l + 1]) l++;
    int local = t - offs[l];
    int N = Ns[l], K = Ks[l];
    int k = local / N, n = local - k * N;
    Wp[(size_t)offs[l] + (size_t)n * K + k] = __float2half(Ws[l][local]);
}

// ---------------------------------------------------------------- MFMA GEMM
// ABN:   A is fp32 conv-out; BN scale/shift+ReLU applied during LDS staging.
// else:  A is fp16 row-major.
// OUT16: C fp16 = dis[row]*acc (staged agg operand). else: C fp32 = acc+bias.
// SLC:   OUT16 writes slice-major [slice16][node][16] (agg L2-residency layout).

template<int NT, bool OUT16, bool ABN, bool SLC>
__global__ __launch_bounds__(256) void k_mgemm(const void* __restrict__ Av,
                                               const __half* __restrict__ Wp,
                                               void* __restrict__ Cv,
                                               int M, int K, int N,
                                               const float* __restrict__ dis,
                                               const float* __restrict__ bias,
                                               const float* __restrict__ AB) {
    constexpr int TN = NT * 16;
    __shared__ __half Ash[128][40];
    __shared__ __half Bsh[TN][40];
    int tid  = threadIdx.x;
    int wave = tid >> 6;
    int lane = tid & 63;
    int quad = lane >> 4;
    int l16  = lane & 15;
    int bm = blockIdx.x * 128;
    int bn = blockIdx.y * TN;

    floatx4 acc[2][NT];
    #pragma unroll
    for (int mt = 0; mt < 2; mt++)
        #pragma unroll
        for (int nt = 0; nt < NT; nt++)
            acc[mt][nt] = (floatx4){0.f, 0.f, 0.f, 0.f};

    for (int k0 = 0; k0 < K; k0 += 32) {
        #pragma unroll
        for (int it = 0; it < 2; it++) {
            int u = tid + it * 256;
            int row = u >> 2, seg = u & 3;
            int grow = bm + row;
            if (ABN) {
                const float* Af = (const float*)Av;
                int f0 = k0 + seg * 8;
                uint4 o = make_uint4(0, 0, 0, 0);
                if (grow < M) {
                    float4 x0 = *(const float4*)&Af[(size_t)grow * K + f0];
                    float4 x1 = *(const float4*)&Af[(size_t)grow * K + f0 + 4];
                    float4 a0 = *(const float4*)&AB[f0];
                    float4 a1 = *(const float4*)&AB[f0 + 4];
                    float4 c0 = *(const float4*)&AB[K + f0];
                    float4 c1 = *(const float4*)&AB[K + f0 + 4];
                    float h0 = fmaxf(x0.x * a0.x + c0.x, 0.f);
                    float h1 = fmaxf(x0.y * a0.y + c0.y, 0.f);
                    float h2 = fmaxf(x0.z * a0.z + c0.z, 0.f);
                    float h3 = fmaxf(x0.w * a0.w + c0.w, 0.f);
                    float h4 = fmaxf(x1.x * a1.x + c1.x, 0.f);
                    float h5 = fmaxf(x1.y * a1.y + c1.y, 0.f);
                    float h6 = fmaxf(x1.z * a1.z + c1.z, 0.f);
                    float h7 = fmaxf(x1.w * a1.w + c1.w, 0.f);
                    union { __half2 h; unsigned u; } p0, p1, p2, p3;
                    p0.h = __floats2half2_rn(h0, h1);
                    p1.h = __floats2half2_rn(h2, h3);
                    p2.h = __floats2half2_rn(h4, h5);
                    p3.h = __floats2half2_rn(h6, h7);
                    o = make_uint4(p0.u, p1.u, p2.u, p3.u);
                }
                *(uint4*)&Ash[row][seg * 8] = o;
            } else {
                const __half* A = (const __half*)Av;
                uint4 v = make_uint4(0, 0, 0, 0);
                if (grow < M) v = *(const uint4*)&A[(size_t)grow * K + k0 + seg * 8];
                *(uint4*)&Ash[row][seg * 8] = v;
            }
        }
        if (tid < TN * 4) {
            int n = tid >> 2, seg = tid & 3;
            uint4 v = *(const uint4*)&Wp[(size_t)(bn + n) * K + k0 + seg * 8];
            *(uint4*)&Bsh[n][seg * 8] = v;
        }
        __syncthreads();
        half8 a[2], b[NT];
        #pragma unroll
        for (int mt = 0; mt < 2; mt++)
            a[mt] = *(const half8*)&Ash[wave * 32 + mt * 16 + l16][quad * 8];
        #pragma unroll
        for (int nt = 0; nt < NT; nt++)
            b[nt] = *(const half8*)&Bsh[nt * 16 + l16][quad * 8];
        #pragma unroll
        for (int mt = 0; mt < 2; mt++)
            #pragma unroll
            for (int nt = 0; nt < NT; nt++)
                acc[mt][nt] = __builtin_amdgcn_mfma_f32_16x16x32_f16(
                    a[mt], b[nt], acc[mt][nt], 0, 0, 0);
        __syncthreads();
    }

    #pragma unroll
    for (int mt = 0; mt < 2; mt++) {
        #pragma unroll
        for (int r = 0; r < 4; r++) {
            int grow = bm + wave * 32 + mt * 16 + quad * 4 + r;
            if (grow >= M) continue;
            if (OUT16) {
                float ds = dis[grow];
                __half* C = (__half*)Cv;
                #pragma unroll
                for (int nt = 0; nt < NT; nt++) {
                    int gcol = bn + nt * 16 + l16;
                    size_t addr = SLC
                        ? (size_t)(gcol >> 4) * ((size_t)NN * 16) + (size_t)grow * 16 + l16
                        : (size_t)grow * N + gcol;
                    C[addr] = __float2half(ds * acc[mt][nt][r]);
                }
            } else {
                float* C = (float*)Cv;
                #pragma unroll
                for (int nt = 0; nt < NT; nt++) {
                    int gcol = bn + nt * 16 + l16;
                    C[(size_t)grow * N + gcol] = acc[mt][nt][r] + bias[gcol];
                }
            }
        }
    }
}

// L1 producer: fused BN+ReLU+dis-scale -> fp16 SLICE-MAJOR (d=128)
__global__ void k_nscale_sl(const float* __restrict__ X, const float* __restrict__ AB,
                            const float* __restrict__ dis, uint4* __restrict__ out) {
    int t = blockIdx.x * blockDim.x + threadIdx.x;
    if (t >= NN * 16) return;
    int row = t >> 4;
    int sub = t & 15;
    int f0 = sub * 8;
    float ds = dis[row];
    float4 x0 = *(const float4*)&X[(size_t)row * 128 + f0];
    float4 x1 = *(const float4*)&X[(size_t)row * 128 + f0 + 4];
    float4 a0 = *(const float4*)&AB[f0];
    float4 a1 = *(const float4*)&AB[f0 + 4];
    float4 c0 = *(const float4*)&AB[128 + f0];
    float4 c1 = *(const float4*)&AB[128 + f0 + 4];
    float h0 = ds * fmaxf(x0.x * a0.x + c0.x, 0.f);
    float h1 = ds * fmaxf(x0.y * a0.y + c0.y, 0.f);
    float h2 = ds * fmaxf(x0.z * a0.z + c0.z, 0.f);
    float h3 = ds * fmaxf(x0.w * a0.w + c0.w, 0.f);
    float h4 = ds * fmaxf(x1.x * a1.x + c1.x, 0.f);
    float h5 = ds * fmaxf(x1.y * a1.y + c1.y, 0.f);
    float h6 = ds * fmaxf(x1.z * a1.z + c1.z, 0.f);
    float h7 = ds * fmaxf(x1.w * a1.w + c1.w, 0.f);
    union { __half2 h; unsigned u; } p0, p1, p2, p3;
    p0.h = __floats2half2_rn(h0, h1);
    p1.h = __floats2half2_rn(h2, h3);
    p2.h = __floats2half2_rn(h4, h5);
    p3.h = __floats2half2_rn(h6, h7);
    out[(size_t)(sub >> 1) * (NN * 2) + (size_t)row * 2 + (sub & 1)] =
        make_uint4(p0.u, p1.u, p2.u, p3.u);
}

// ---------------------------------------------------------------- aggregation
// Lessons pinned:
//  - R7: row slicing below line granularity needs RESIDENCY to pay off.
//  - R8: no contended global atomics in epilogues.
//  - R4: byte-shrinking a latency-bound random gather is worthless.
//  - R5: blockIdx%8 does NOT give XCD affinity, and streamed colv thrashes
//        the slice out of L2. Fix: explicit HW_REG_XCC_ID pinning + work
//        queues (+stealing for placement-independence) + nontemporal
//        loads/stores for all streaming traffic.

__device__ __forceinline__ int xcc_id() {
    unsigned v;
    asm("s_getreg_b32 %0, hwreg(HW_REG_XCC_ID)" : "=s"(v));
    return (int)v;
}

__device__ __forceinline__ void acc_row(float* acc, const uint4& r) {
    const __half2* hp = (const __half2*)&r;
    #pragma unroll
    for (int k = 0; k < 4; k++) {
        float2 f2 = __half22float2(hp[k]);
        acc[2 * k]     += f2.x;
        acc[2 * k + 1] += f2.y;
    }
}

// XCC-pinned slice gather, d=128, NS=8 slices of 16 feats (32B stripe).
// Hs: slice-major fp16 [8][NN][16]; 2 lanes/node. Per-slice work queue wq[s];
// block processes its own XCD's slice first, then steals (correctness never
// depends on placement). colv/outputs nontemporal so L2 holds only the slice.
template<bool OUT16>
__global__ __launch_bounds__(256) void k_agg_x(const uint4* __restrict__ Hs,
                                               void* __restrict__ outv,
                                               const int* __restrict__ rowptr,
                                               const int* __restrict__ degcnt,
                                               const int* __restrict__ colv,
                                               const float* __restrict__ dis,
                                               const float* __restrict__ bias,
                                               int* __restrict__ wq) {
    __shared__ int sblk;
    int xcc  = xcc_id() & 7;
    int g    = threadIdx.x >> 1;
    int lane = threadIdx.x & 1;
    for (int sv = 0; sv < 8; sv++) {
        int s = (xcc + sv) & 7;
        const uint4* base = Hs + (size_t)s * (NN * 2) + lane;
        for (;;) {
            __syncthreads();
            if (threadIdx.x == 0) sblk = atomicAdd(&wq[s], 1);
            __syncthreads();
            int nb = sblk;
            if (nb >= NBLK128) break;
            int i = nb * 128 + g;
            if (i >= NN) continue;
            int beg = rowptr[i];
            int cnt = degcnt[i];
            float acc[8] = {};
            int e = 0;
            for (; e + 8 <= cnt; e += 8) {
                int c[8];
                #pragma unroll
                for (int j = 0; j < 8; j++)
                    c[j] = __builtin_nontemporal_load(&colv[beg + e + j]);
                uint4 r[8];
                #pragma unroll
                for (int j = 0; j < 8; j++) r[j] = base[(size_t)c[j] * 2];
                #pragma unroll
                for (int j = 0; j < 8; j++) acc_row(acc, r[j]);
            }
            for (; e < cnt; e++) {
                int c = __builtin_nontemporal_load(&colv[beg + e]);
                acc_row(acc, base[(size_t)c * 2]);
            }
            acc_row(acc, base[(size_t)i * 2]);  // self-loop
            float ds = dis[i];
            float o[8];
            #pragma unroll
            for (int k = 0; k < 8; k++) o[k] = ds * acc[k];
            if (OUT16) {
                uint4 ov;
                __half2* op = (__half2*)&ov;
                #pragma unroll
                for (int k = 0; k < 4; k++)
                    op[k] = __floats2half2_rn(o[2 * k], o[2 * k + 1]);
                nt_store_u4(ov, &((uint4*)outv)[(size_t)i * 16 + s * 2 + lane]);
            } else {
                const float4* bi = (const float4*)bias;
                float4 b0 = bi[s * 4 + lane * 2];
                float4 b1 = bi[s * 4 + lane * 2 + 1];
                float4* out = (float4*)outv;
                size_t ob = (size_t)i * 32 + s * 4 + lane * 2;
                nt_store_f4(make_float4(o[0] + b0.x, o[1] + b0.y,
                                        o[2] + b0.z, o[3] + b0.w), &out[ob]);
                nt_store_f4(make_float4(o[4] + b1.x, o[5] + b1.y,
                                        o[6] + b1.z, o[7] + b1.w), &out[ob + 1]);
            }
        }
    }
}

// fp16 full-row gather (16B/thread, TPN = d/8 threads/node) — late layers
template<int TPN, bool OUT16>
__global__ __launch_bounds__(256) void k_agg_h(const uint4* __restrict__ Hs,
                                               void* __restrict__ outv,
                                               const int* __restrict__ rowptr,
                                               const int* __restrict__ degcnt,
                                               const int* __restrict__ colv,
                                               const float* __restrict__ dis,
                                               const float* __restrict__ bias) {
    constexpr int G = 256 / TPN;
    int g    = threadIdx.x / TPN;
    int lane = threadIdx.x % TPN;
    int i = blockIdx.x * G + g;
    if (i >= NN) return;
    int beg = rowptr[i];
    int cnt = degcnt[i];
    const uint4* base = Hs + lane;
    float acc[8] = {};
    int e = 0;
    for (; e + 8 <= cnt; e += 8) {
        int c[8];
        #pragma unroll
        for (int j = 0; j < 8; j++) c[j] = colv[beg + e + j];
        uint4 r[8];
        #pragma unroll
        for (int j = 0; j < 8; j++) r[j] = base[(size_t)c[j] * TPN];
        #pragma unroll
        for (int j = 0; j < 8; j++) acc_row(acc, r[j]);
    }
    for (; e < cnt; e++) {
        uint4 r = base[(size_t)colv[beg + e] * TPN];
        acc_row(acc, r);
    }
    uint4 rs = base[(size_t)i * TPN];  // self-loop
    acc_row(acc, rs);
    float ds = dis[i];
    float o[8];
    #pragma unroll
    for (int k = 0; k < 8; k++) o[k] = ds * acc[k];
    if (OUT16) {
        uint4 ov;
        __half2* op = (__half2*)&ov;
        #pragma unroll
        for (int k = 0; k < 4; k++) op[k] = __floats2half2_rn(o[2 * k], o[2 * k + 1]);
        ((uint4*)outv)[(size_t)i * TPN + lane] = ov;
    } else {
        float4 b0 = ((const float4*)bias)[lane * 2];
        float4 b1 = ((const float4*)bias)[lane * 2 + 1];
        o[0] += b0.x; o[1] += b0.y; o[2] += b0.z; o[3] += b0.w;
        o[4] += b1.x; o[5] += b1.y; o[6] += b1.z; o[7] += b1.w;
        float4* out = (float4*)outv;
        size_t ob = (size_t)i * (2 * TPN) + lane * 2;
        out[ob]     = make_float4(o[0], o[1], o[2], o[3]);
        out[ob + 1] = make_float4(o[4], o[5], o[6], o[7]);
    }
}

// ---------------------------------------------------------------- BatchNorm
// Atomic-free two-phase tree (R8 lesson: contended atomics are the enemy).

template<int D>
__global__ __launch_bounds__(256) void k_bnpart(const float4* __restrict__ X4,
                                                float* __restrict__ partial) {
    constexpr int Q   = D / 4;
    constexpr int RPI = 256 / Q;
    int tq = threadIdx.x % Q;
    int rg = threadIdx.x / Q;
    int chunk = (NN + BNBLK - 1) / BNBLK;
    int r0 = blockIdx.x * chunk;
    int r1 = r0 + chunk; if (r1 > NN) r1 = NN;
    float4 s  = {0.f, 0.f, 0.f, 0.f};
    float4 s2 = {0.f, 0.f, 0.f, 0.f};
    for (int r = r0 + rg; r < r1; r += RPI) {
        float4 v = X4[(size_t)r * Q + tq];
        s.x += v.x; s.y += v.y; s.z += v.z; s.w += v.w;
        s2.x += v.x * v.x; s2.y += v.y * v.y; s2.z += v.z * v.z; s2.w += v.w * v.w;
    }
    __shared__ float4 ls[256], ls2[256];
    ls[threadIdx.x] = s; ls2[threadIdx.x] = s2;
    __syncthreads();
    if (threadIdx.x < Q) {
        float4 a = ls[threadIdx.x], b = ls2[threadIdx.x];
        #pragma unroll
        for (int g = 1; g < RPI; g++) {
            float4 u = ls[g * Q + threadIdx.x], w = ls2[g * Q + threadIdx.x];
            a.x += u.x; a.y += u.y; a.z += u.z; a.w += u.w;
            b.x += w.x; b.y += w.y; b.z += w.z; b.w += w.w;
        }
        *(float4*)&partial[(size_t)blockIdx.x * 2 * D + threadIdx.x * 4]     = a;
        *(float4*)&partial[(size_t)blockIdx.x * 2 * D + D + threadIdx.x * 4] = b;
    }
}

// parallel final reduce: 1024 threads, G=1024/D groups strided over partials
template<int D>
__global__ __launch_bounds__(1024) void k_bnfin2(const float* __restrict__ partial,
                                                 const float* __restrict__ g,
                                                 const float* __restrict__ be,
                                                 float* __restrict__ AB) {
    constexpr int G = 1024 / D;
    int f  = threadIdx.x % D;
    int gr = threadIdx.x / D;
    float sum = 0.f, sq = 0.f;
    for (int b = gr; b < BNBLK; b += G) {
        sum += partial[(size_t)b * 2 * D + f];
        sq  += partial[(size_t)b * 2 * D + D + f];
    }
    __shared__ float ls[1024], ls2[1024];
    ls[threadIdx.x] = sum; ls2[threadIdx.x] = sq;
    __syncthreads();
    if (threadIdx.x < D) {
        float a = ls[threadIdx.x], b = ls2[threadIdx.x];
        for (int k = 1; k < G; k++) {
            a += ls[k * D + threadIdx.x];
            b += ls2[k * D + threadIdx.x];
        }
        float mu  = a / (float)NN;
        float var = b / (float)NN - mu * mu;
        var = fmaxf(var, 0.f);
        float inv = rsqrtf(var + EPSB);
        float sc = g[threadIdx.x] * inv;
        AB[threadIdx.x]     = sc;
        AB[D + threadIdx.x] = be[threadIdx.x] - mu * sc;
    }
}

__global__ void k_norm16(const float4* __restrict__ X, const float* __restrict__ AB,
                         uint2* __restrict__ Y, int d, int total4) {
    int t = blockIdx.x * blockDim.x + threadIdx.x;
    if (t >= total4) return;
    int f0 = (t * 4) & (d - 1);
    float4 v = X[t];
    float a0 = AB[f0],     a1 = AB[f0 + 1], a2 = AB[f0 + 2], a3 = AB[f0 + 3];
    float c0 = AB[d + f0], c1 = AB[d + f0 + 1], c2 = AB[d + f0 + 2], c3 = AB[d + f0 + 3];
    float o0 = fmaxf(v.x * a0 + c0, 0.f);
    float o1 = fmaxf(v.y * a1 + c1, 0.f);
    float o2 = fmaxf(v.z * a2 + c2, 0.f);
    float o3 = fmaxf(v.w * a3 + c3, 0.f);
    union { __half2 h; unsigned u; } p, q;
    p.h = __floats2half2_rn(o0, o1);
    q.h = __floats2half2_rn(o2, o3);
    Y[t] = make_uint2(p.u, q.u);
}

// ---------------------------------------------------------------- final edge MLP

__global__ __launch_bounds__(256) void k_edge16(const uint4* __restrict__ X,
                                                const int* __restrict__ src,
                                                const int* __restrict__ dst,
                                                const float* __restrict__ fcw,
                                                const float* __restrict__ fcb,
                                                float* __restrict__ out) {
    int lane = threadIdx.x & 3;
    size_t t = (size_t)blockIdx.x * 256 + threadIdx.x;
    int eid = (int)(t >> 2);
    if (eid >= EE) return;
    int s = src[eid], d = dst[eid];
    uint4 av = X[(size_t)s * 4 + lane];
    uint4 bv = X[(size_t)d * 4 + lane];
    const __half2* ap = (const __half2*)&av;
    const __half2* bp2 = (const __half2*)&bv;
    float v = 0.f;
    #pragma unroll
    for (int k = 0; k < 4; k++) {
        float2 fa = __half22float2(ap[k]);
        float2 fb = __half22float2(bp2[k]);
        float w0 = fcw[lane * 8 + 2 * k];
        float w1 = fcw[lane * 8 + 2 * k + 1];
        v += fa.x * fb.x * w0 + fa.y * fb.y * w1;
    }
    v += __shfl_xor(v, 1, 4);
    v += __shfl_xor(v, 2, 4);
    if (lane == 0) out[eid] = 1.f / (1.f + expf(-(v + fcb[0])));
}

// ---------------------------------------------------------------- launch

extern "C" void kernel_launch(void* const* d_in, const int* in_sizes, int n_in,
                              void* d_out, int out_size, void* d_ws, size_t ws_size,
                              hipStream_t stream) {
    const float* x0 = (const float*)d_in[0];
    const int* ei   = (const int*)d_in[1];
    const int* srcv = ei;
    const int* dstv = ei + EE;
    const float *W[5], *bp[5], *gp[5], *bep[5];
    int idx = 2;
    for (int l = 0; l < 5; l++) {
        W[l]   = (const float*)d_in[idx++];
        bp[l]  = (const float*)d_in[idx++];
        gp[l]  = (const float*)d_in[idx++];
        bep[l] = (const float*)d_in[idx++];
    }
    const float* fcw = (const float*)d_in[22];
    const float* fcb = (const float*)d_in[23];

    char* ws = (char*)d_ws;
    size_t off = 0;
    auto alloc = [&](size_t bytes) -> void* {
        void* p = ws + off;
        off = (off + bytes + 255) & ~(size_t)255;
        return p;
    };
    float*    bufA    = (float*)   alloc((size_t)NN * 256 * 4);
    __half*   act16   = (__half*)  alloc((size_t)NN * 256 * 2);
    __half*   x16     = (__half*)  alloc((size_t)NN * 128 * 2);
    __half*   Hh      = (__half*)  alloc((size_t)NN * 128 * 2);
    unsigned* barr    = (unsigned*)alloc((size_t)NB * BCAP * 4);
    int*      colv    = (int*)     alloc((size_t)EE * 4);
    int*      rowptr  = (int*)     alloc((size_t)NN * 4);
    int*      degcnt  = (int*)     alloc((size_t)NN * 4);
    float*    dis     = (float*)   alloc((size_t)NN * 4);
    int*      bcur    = (int*)     alloc((size_t)NB * 4);
    int*      scnblk  = (int*)     alloc(4096);
    float*    bnpart  = (float*)   alloc((size_t)BNBLK * 512 * 4);  // 1 MB
    float*    bnAB    = (float*)   alloc(512 * 4);
    __half*   Wp      = (__half*)  alloc((size_t)92160 * 2);
    int*      wq      = (int*)     alloc(3 * 8 * 4);   // 3 agg work-queue sets
    const int woff[5] = {0, 16384, 49152, 81920, 90112};

    // ---- CSR build (binned counting sort)
    hipMemsetAsync(bcur, 0, (size_t)NB * 4, stream);
    hipMemsetAsync(wq, 0, 3 * 8 * 4, stream);
    k_bscat<<<(EE + 4095) / 4096, 256, 0, stream>>>(srcv, dstv, bcur, barr);
    k_bdeg<<<NB, 1024, 0, stream>>>(bcur, barr, degcnt, dis);
    int nScanBlk = (NN + 1023) / 1024;
    k_scan_block<<<nScanBlk, 1024, 0, stream>>>(degcnt, rowptr, scnblk, NN);
    k_scan_top<<<1, 64, 0, stream>>>(scnblk, nScanBlk);
    k_scan_add<<<nScanBlk, 1024, 0, stream>>>(rowptr, scnblk, NN);
    k_place<<<NB, 1024, 0, stream>>>(bcur, barr, rowptr, colv);

    // ---- casts / weight packs
    k_f2h<<<(NN * 128 / 4 + 255) / 256, 256, 0, stream>>>(
        (const float4*)x0, (uint2*)x16, NN * 128 / 4);
    k_wpack_all<<<(92160 + 255) / 256, 256, 0, stream>>>(W[0], W[1], W[2], W[3], W[4], Wp);

    int gx = (NN + 127) / 128;

    // ---- layer 0: mgemm(x16)->Hh[slice] ; agg_x(+b0)->bufA ; bn ; nscale_sl->Hh[slice]
    {
        dim3 grid(gx, 128 / 64);
        k_mgemm<4, true, false, true><<<grid, 256, 0, stream>>>(
            x16, Wp + woff[0], Hh, NN, 128, 128, dis, nullptr, nullptr);
        k_agg_x<false><<<2048, 256, 0, stream>>>(
            (const uint4*)Hh, bufA, rowptr, degcnt, colv, dis, bp[0], wq);
        k_bnpart<128><<<BNBLK, 256, 0, stream>>>((const float4*)bufA, bnpart);
        k_bnfin2<128><<<1, 1024, 0, stream>>>(bnpart, gp[0], bep[0], bnAB);
        k_nscale_sl<<<(NN * 16 + 255) / 256, 256, 0, stream>>>(bufA, bnAB, dis, (uint4*)Hh);
    }
    // ---- layer 1 (agg first): agg_x OUT16->act16 ; mgemm(act16,+b1)->bufA ; bn
    {
        k_agg_x<true><<<2048, 256, 0, stream>>>(
            (const uint4*)Hh, act16, rowptr, degcnt, colv, dis, nullptr, wq + 8);
        dim3 grid(gx, 256 / 64);
        k_mgemm<4, false, false, false><<<grid, 256, 0, stream>>>(
            act16, Wp + woff[1], bufA, NN, 128, 256, nullptr, bp[1], nullptr);
        k_bnpart<256><<<BNBLK, 256, 0, stream>>>((const float4*)bufA, bnpart);
        k_bnfin2<256><<<1, 1024, 0, stream>>>(bnpart, gp[1], bep[1], bnAB);
    }
    // ---- layer 2: mgemm(ABN: bufA d=256)->Hh[slice] ; agg_x(+b2)->bufA ; bn
    {
        dim3 grid(gx, 128 / 64);
        k_mgemm<4, true, true, true><<<grid, 256, 0, stream>>>(
            bufA, Wp + woff[2], Hh, NN, 256, 128, dis, nullptr, bnAB);
        k_agg_x<false><<<2048, 256, 0, stream>>>(
            (const uint4*)Hh, bufA, rowptr, degcnt, colv, dis, bp[2], wq + 16);
        k_bnpart<128><<<BNBLK, 256, 0, stream>>>((const float4*)bufA, bnpart);
        k_bnfin2<128><<<1, 1024, 0, stream>>>(bnpart, gp[2], bep[2], bnAB);
    }
    // ---- layer 3 (d=64, fp16 row agg): mgemm(ABN: bufA d=128)->Hh ; agg(+b3)->bufA ; bn
    {
        dim3 grid(gx, 64 / 64);
        k_mgemm<4, true, true, false><<<grid, 256, 0, stream>>>(
            bufA, Wp + woff[3], Hh, NN, 128, 64, dis, nullptr, bnAB);
        k_agg_h<8, false><<<(NN + 31) / 32, 256, 0, stream>>>(
            (const uint4*)Hh, bufA, rowptr, degcnt, colv, dis, bp[3]);
        k_bnpart<64><<<BNBLK, 256, 0, stream>>>((const float4*)bufA, bnpart);
        k_bnfin2<64><<<1, 1024, 0, stream>>>(bnpart, gp[3], bep[3], bnAB);
    }
    // ---- layer 4 (d=32, fp16 row agg): mgemm(ABN: bufA d=64)->Hh ; agg(+b4)->bufA ; bn ; norm16
    {
        dim3 grid(gx, 1);
        k_mgemm<2, true, true, false><<<grid, 256, 0, stream>>>(
            bufA, Wp + woff[4], Hh, NN, 64, 32, dis, nullptr, bnAB);
        k_agg_h<4, false><<<(NN + 63) / 64, 256, 0, stream>>>(
            (const uint4*)Hh, bufA, rowptr, degcnt, colv, dis, bp[4]);
        k_bnpart<32><<<BNBLK, 256, 0, stream>>>((const float4*)bufA, bnpart);
        k_bnfin2<32><<<1, 1024, 0, stream>>>(bnpart, gp[4], bep[4], bnAB);
        int total4 = NN * 32 / 4;
        k_norm16<<<(total4 + 255) / 256, 256, 0, stream>>>(
            (const float4*)bufA, bnAB, (uint2*)act16, 32, total4);
    }

    size_t edgeThreads = (size_t)EE * 4;
    k_edge16<<<(unsigned)((edgeThreads + 255) / 256), 256, 0, stream>>>(
        (const uint4*)act16, srcv, dstv, fcw, fcb, (float*)d_out);
}

// Round 8
// 1248.180 us; speedup vs baseline: 1.5484x; 1.5484x over previous
//
#include <hip/hip_runtime.h>
#include <hip/hip_fp16.h>
#include <cstddef>

#define NN 100000
#define EE 3200000
#define EPSB 1e-5f
#define NB 391      // buckets = ceil(NN/256)
#define BCAP 10240  // per-bucket edge capacity
#define BNBLK 512   // BN partial blocks for the L1 GEMM path

typedef _Float16 half8 __attribute__((ext_vector_type(8)));
typedef float floatx4 __attribute__((ext_vector_type(4)));

// ---------------------------------------------------------------- CSR build
// packed record: src (17 bits) | dst&255 (8 bits) << 17

__global__ __launch_bounds__(256) void k_bscat(const int* __restrict__ src,
                                               const int* __restrict__ dst,
                                               int* __restrict__ bcur,
                                               unsigned* __restrict__ barr) {
    __shared__ int hist[NB];
    __shared__ int base[NB];
    int tid = threadIdx.x;
    for (int b = tid; b < NB; b += 256) hist[b] = 0;
    __syncthreads();
    int e0 = blockIdx.x * 4096;
    int d[16], s[16];
    #pragma unroll
    for (int j = 0; j < 16; j++) {
        int e = e0 + j * 256 + tid;
        if (e < EE) {
            d[j] = dst[e];
            s[j] = src[e];
            atomicAdd(&hist[d[j] >> 8], 1);
        } else d[j] = -1;
    }
    __syncthreads();
    for (int b = tid; b < NB; b += 256) {
        int c = hist[b];
        base[b] = (c > 0) ? atomicAdd(&bcur[b], c) : 0;
        hist[b] = 0;
    }
    __syncthreads();
    #pragma unroll
    for (int j = 0; j < 16; j++) {
        if (d[j] >= 0) {
            int b = d[j] >> 8;
            int r = atomicAdd(&hist[b], 1);
            barr[(size_t)b * BCAP + base[b] + r] =
                (unsigned)s[j] | ((unsigned)(d[j] & 255) << 17);
        }
    }
}

__global__ __launch_bounds__(1024) void k_bdeg(const int* __restrict__ bcur,
                                               const unsigned* __restrict__ barr,
                                               int* __restrict__ degcnt,
                                               float* __restrict__ dis) {
    __shared__ int h[256];
    int b = blockIdx.x;
    if (threadIdx.x < 256) h[threadIdx.x] = 0;
    __syncthreads();
    int cnt = bcur[b];
    const unsigned* p = barr + (size_t)b * BCAP;
    for (int t = threadIdx.x; t < cnt; t += 1024)
        atomicAdd(&h[(p[t] >> 17) & 255], 1);
    __syncthreads();
    if (threadIdx.x < 256) {
        int node = (b << 8) + threadIdx.x;
        if (node < NN) {
            int dg = h[threadIdx.x];
            degcnt[node] = dg;
            dis[node] = rsqrtf((float)dg + 1.0f);
        }
    }
}

__global__ __launch_bounds__(1024) void k_place(const int* __restrict__ bcur,
                                                const unsigned* __restrict__ barr,
                                                const int* __restrict__ rowptr,
                                                int* __restrict__ col) {
    __shared__ int cur[256];
    int b = blockIdx.x;
    if (threadIdx.x < 256) {
        int node = (b << 8) + threadIdx.x;
        cur[threadIdx.x] = (node < NN) ? rowptr[node] : 0;
    }
    __syncthreads();
    int cnt = bcur[b];
    const unsigned* p = barr + (size_t)b * BCAP;
    for (int t = threadIdx.x; t < cnt; t += 1024) {
        unsigned e = p[t];
        int pos = atomicAdd(&cur[(e >> 17) & 255], 1);
        col[pos] = (int)(e & 0x1FFFFu);
    }
}

__global__ void k_scan_block(const int* __restrict__ in, int* __restrict__ out,
                             int* __restrict__ blksum, int n) {
    __shared__ int s[1024];
    int i = blockIdx.x * 1024 + threadIdx.x;
    int v = (i < n) ? in[i] : 0;
    s[threadIdx.x] = v;
    __syncthreads();
    for (int off = 1; off < 1024; off <<= 1) {
        int t = (threadIdx.x >= off) ? s[threadIdx.x - off] : 0;
        __syncthreads();
        s[threadIdx.x] += t;
        __syncthreads();
    }
    if (i < n) out[i] = s[threadIdx.x] - v;  // exclusive
    if (threadIdx.x == 1023) blksum[blockIdx.x] = s[1023];
}

__global__ void k_scan_top(int* __restrict__ blksum, int nb) {
    if (threadIdx.x == 0) {
        int acc = 0;
        for (int b = 0; b < nb; b++) { int v = blksum[b]; blksum[b] = acc; acc += v; }
    }
}

__global__ void k_scan_add(int* __restrict__ out, const int* __restrict__ blksum, int n) {
    int i = blockIdx.x * 1024 + threadIdx.x;
    if (i < n) out[i] += blksum[blockIdx.x];
}

// ---------------------------------------------------------------- casts / packing

__global__ void k_f2h(const float4* __restrict__ in, uint2* __restrict__ out, int n4) {
    int t = blockIdx.x * blockDim.x + threadIdx.x;
    if (t >= n4) return;
    float4 v = in[t];
    union { __half2 h; unsigned u; } a, b;
    a.h = __floats2half2_rn(v.x, v.y);
    b.h = __floats2half2_rn(v.z, v.w);
    out[t] = make_uint2(a.u, b.u);
}

__global__ void k_wpack_all(const float* __restrict__ W0, const float* __restrict__ W1,
                            const float* __restrict__ W2, const float* __restrict__ W3,
                            const float* __restrict__ W4, __half* __restrict__ Wp) {
    const int offs[6] = {0, 16384, 49152, 81920, 90112, 92160};
    const int Ks[5] = {128, 128, 256, 128, 64};
    const int Ns[5] = {128, 256, 128, 64, 32};
    const float* Ws[5] = {W0, W1, W2, W3, W4};
    int t = blockIdx.x * blockDim.x + threadIdx.x;
    if (t >= 92160) return;
    int l = 0;
    while (t >= offs[l + 1]) l++;
    int local = t - offs[l];
    int N = Ns[l], K = Ks[l];
    int k = local / N, n = local - k * N;
    Wp[(size_t)offs[l] + (size_t)n * K + k] = __float2half(Ws[l][local]);
}

// ---------------------------------------------------------------- MFMA GEMM
// modes: OUT16: C fp16 = dis*acc (agg operand, Hh). CH16: C fp16 = acc+bias
// (conv-out). ABN: BN+ReLU during A staging; AH16: ABN input is fp16.

template<int NT, bool OUT16, bool ABN, bool AH16, bool CH16>
__global__ __launch_bounds__(256) void k_mgemm(const void* __restrict__ Av,
                                               const __half* __restrict__ Wp,
                                               void* __restrict__ Cv,
                                               int M, int K, int N,
                                               const float* __restrict__ dis,
                                               const float* __restrict__ bias,
                                               const float* __restrict__ AB) {
    constexpr int TN = NT * 16;
    __shared__ __half Ash[128][40];
    __shared__ __half Bsh[TN][40];
    int tid  = threadIdx.x;
    int wave = tid >> 6;
    int lane = tid & 63;
    int quad = lane >> 4;
    int l16  = lane & 15;
    int bm = blockIdx.x * 128;
    int bn = blockIdx.y * TN;

    floatx4 acc[2][NT];
    #pragma unroll
    for (int mt = 0; mt < 2; mt++)
        #pragma unroll
        for (int nt = 0; nt < NT; nt++)
            acc[mt][nt] = (floatx4){0.f, 0.f, 0.f, 0.f};

    for (int k0 = 0; k0 < K; k0 += 32) {
        #pragma unroll
        for (int it = 0; it < 2; it++) {
            int u = tid + it * 256;
            int row = u >> 2, seg = u & 3;
            int grow = bm + row;
            if (ABN) {
                int f0 = k0 + seg * 8;
                uint4 o = make_uint4(0, 0, 0, 0);
                if (grow < M) {
                    float x[8];
                    if (AH16) {
                        const __half* Af = (const __half*)Av;
                        uint4 xv = *(const uint4*)&Af[(size_t)grow * K + f0];
                        const __half2* xp = (const __half2*)&xv;
                        #pragma unroll
                        for (int k = 0; k < 4; k++) {
                            float2 f = __half22float2(xp[k]);
                            x[2 * k] = f.x; x[2 * k + 1] = f.y;
                        }
                    } else {
                        const float* Af = (const float*)Av;
                        float4 x0 = *(const float4*)&Af[(size_t)grow * K + f0];
                        float4 x1 = *(const float4*)&Af[(size_t)grow * K + f0 + 4];
                        x[0] = x0.x; x[1] = x0.y; x[2] = x0.z; x[3] = x0.w;
                        x[4] = x1.x; x[5] = x1.y; x[6] = x1.z; x[7] = x1.w;
                    }
                    float4 a0 = *(const float4*)&AB[f0];
                    float4 a1 = *(const float4*)&AB[f0 + 4];
                    float4 c0 = *(const float4*)&AB[K + f0];
                    float4 c1 = *(const float4*)&AB[K + f0 + 4];
                    float h0 = fmaxf(x[0] * a0.x + c0.x, 0.f);
                    float h1 = fmaxf(x[1] * a0.y + c0.y, 0.f);
                    float h2 = fmaxf(x[2] * a0.z + c0.z, 0.f);
                    float h3 = fmaxf(x[3] * a0.w + c0.w, 0.f);
                    float h4 = fmaxf(x[4] * a1.x + c1.x, 0.f);
                    float h5 = fmaxf(x[5] * a1.y + c1.y, 0.f);
                    float h6 = fmaxf(x[6] * a1.z + c1.z, 0.f);
                    float h7 = fmaxf(x[7] * a1.w + c1.w, 0.f);
                    union { __half2 h; unsigned u; } p0, p1, p2, p3;
                    p0.h = __floats2half2_rn(h0, h1);
                    p1.h = __floats2half2_rn(h2, h3);
                    p2.h = __floats2half2_rn(h4, h5);
                    p3.h = __floats2half2_rn(h6, h7);
                    o = make_uint4(p0.u, p1.u, p2.u, p3.u);
                }
                *(uint4*)&Ash[row][seg * 8] = o;
            } else {
                const __half* A = (const __half*)Av;
                uint4 v = make_uint4(0, 0, 0, 0);
                if (grow < M) v = *(const uint4*)&A[(size_t)grow * K + k0 + seg * 8];
                *(uint4*)&Ash[row][seg * 8] = v;
            }
        }
        if (tid < TN * 4) {
            int n = tid >> 2, seg = tid & 3;
            uint4 v = *(const uint4*)&Wp[(size_t)(bn + n) * K + k0 + seg * 8];
            *(uint4*)&Bsh[n][seg * 8] = v;
        }
        __syncthreads();
        half8 a[2], b[NT];
        #pragma unroll
        for (int mt = 0; mt < 2; mt++)
            a[mt] = *(const half8*)&Ash[wave * 32 + mt * 16 + l16][quad * 8];
        #pragma unroll
        for (int nt = 0; nt < NT; nt++)
            b[nt] = *(const half8*)&Bsh[nt * 16 + l16][quad * 8];
        #pragma unroll
        for (int mt = 0; mt < 2; mt++)
            #pragma unroll
            for (int nt = 0; nt < NT; nt++)
                acc[mt][nt] = __builtin_amdgcn_mfma_f32_16x16x32_f16(
                    a[mt], b[nt], acc[mt][nt], 0, 0, 0);
        __syncthreads();
    }

    #pragma unroll
    for (int mt = 0; mt < 2; mt++) {
        #pragma unroll
        for (int r = 0; r < 4; r++) {
            int grow = bm + wave * 32 + mt * 16 + quad * 4 + r;
            if (grow >= M) continue;
            if (OUT16) {
                float ds = dis[grow];
                __half* C = (__half*)Cv;
                #pragma unroll
                for (int nt = 0; nt < NT; nt++) {
                    int gcol = bn + nt * 16 + l16;
                    C[(size_t)grow * N + gcol] = __float2half(ds * acc[mt][nt][r]);
                }
            } else if (CH16) {
                __half* C = (__half*)Cv;
                #pragma unroll
                for (int nt = 0; nt < NT; nt++) {
                    int gcol = bn + nt * 16 + l16;
                    C[(size_t)grow * N + gcol] = __float2half(acc[mt][nt][r] + bias[gcol]);
                }
            } else {
                float* C = (float*)Cv;
                #pragma unroll
                for (int nt = 0; nt < NT; nt++) {
                    int gcol = bn + nt * 16 + l16;
                    C[(size_t)grow * N + gcol] = acc[mt][nt][r] + bias[gcol];
                }
            }
        }
    }
}

// ---------------------------------------------------------------- int8 quant
// L0 operand: signed, per-8-feature scales; L1 operand: unsigned per-16.
// (verified R3 structure)

__global__ __launch_bounds__(256) void k_q8p8(const uint4* __restrict__ H,
                                              uint2* __restrict__ q8,
                                              float* __restrict__ scq, int total) {
    int t = blockIdx.x * 256 + threadIdx.x;
    if (t >= total) return;
    uint4 v = H[t];
    const __half2* hp = (const __half2*)&v;
    float h[8];
    #pragma unroll
    for (int k = 0; k < 4; k++) {
        float2 f = __half22float2(hp[k]);
        h[2 * k] = f.x; h[2 * k + 1] = f.y;
    }
    float m = fabsf(h[0]);
    #pragma unroll
    for (int k = 1; k < 8; k++) m = fmaxf(m, fabsf(h[k]));
    float inv = m > 0.f ? 127.f / m : 0.f;
    unsigned b[8];
    #pragma unroll
    for (int k = 0; k < 8; k++) {
        float f = fminf(fmaxf(h[k] * inv, -127.f), 127.f);
        b[k] = (unsigned)(f + 128.5f);
    }
    q8[t] = make_uint2(b[0] | (b[1] << 8) | (b[2] << 16) | (b[3] << 24),
                       b[4] | (b[5] << 8) | (b[6] << 16) | (b[7] << 24));
    scq[t] = m * (1.f / 127.f);
}

// L1 fused BN+ReLU+dis-scale -> unsigned q8 (d=128, 16 threads/row), fp16 input
__global__ void k_nscale_q8(const __half* __restrict__ X, const float* __restrict__ AB,
                            const float* __restrict__ dis, uint2* __restrict__ q8,
                            float* __restrict__ scq) {
    int t = blockIdx.x * blockDim.x + threadIdx.x;
    if (t >= NN * 16) return;
    int row = t >> 4;
    int sub = t & 15;
    int f0 = sub * 8;
    float ds = dis[row];
    uint4 xv = ((const uint4*)X)[(size_t)row * 16 + sub];
    const __half2* xp = (const __half2*)&xv;
    float x[8];
    #pragma unroll
    for (int k = 0; k < 4; k++) {
        float2 f = __half22float2(xp[k]);
        x[2 * k] = f.x; x[2 * k + 1] = f.y;
    }
    float4 a0 = *(const float4*)&AB[f0];
    float4 a1 = *(const float4*)&AB[f0 + 4];
    float4 c0 = *(const float4*)&AB[128 + f0];
    float4 c1 = *(const float4*)&AB[128 + f0 + 4];
    float h[8];
    h[0] = ds * fmaxf(x[0] * a0.x + c0.x, 0.f);
    h[1] = ds * fmaxf(x[1] * a0.y + c0.y, 0.f);
    h[2] = ds * fmaxf(x[2] * a0.z + c0.z, 0.f);
    h[3] = ds * fmaxf(x[3] * a0.w + c0.w, 0.f);
    h[4] = ds * fmaxf(x[4] * a1.x + c1.x, 0.f);
    h[5] = ds * fmaxf(x[5] * a1.y + c1.y, 0.f);
    h[6] = ds * fmaxf(x[6] * a1.z + c1.z, 0.f);
    h[7] = ds * fmaxf(x[7] * a1.w + c1.w, 0.f);
    float m = h[0];
    #pragma unroll
    for (int k = 1; k < 8; k++) m = fmaxf(m, h[k]);
    m = fmaxf(m, __shfl_xor(m, 1));   // 16-feat group max
    float inv = m > 0.f ? 255.f / m : 0.f;
    unsigned b[8];
    #pragma unroll
    for (int k = 0; k < 8; k++)
        b[k] = (unsigned)(fminf(h[k] * inv, 255.f) + 0.5f);
    q8[t] = make_uint2(b[0] | (b[1] << 8) | (b[2] << 16) | (b[3] << 24),
                       b[4] | (b[5] << 8) | (b[6] << 16) | (b[7] << 24));
    if ((t & 1) == 0) scq[t >> 1] = m * (1.f / 255.f);
}

// ---------------------------------------------------------------- aggregation
// Lessons pinned:
//  - R4: byte-shrinking a latency-bound random gather is worthless.
//  - R5/R7: locality engineering (slice residency, XCC pinning) fails; the
//    ~113us/d=128 random-gather floor stands. Optimize the STREAMING side.
//  - R8(this): conv-out stored fp16; BN partials fused into agg epilogue
//    (computed from pre-rounded fp32); alive-flag (no early return: barrier!).

__device__ __forceinline__ void acc_q8s2(float* acc, const uint4& r,
                                         const float2& s, float& c0, float& c1) {
    const unsigned* w = (const unsigned*)&r;
    c0 += s.x; c1 += s.y;
    #pragma unroll
    for (int q = 0; q < 4; q++) {
        unsigned v = w[q];
        float sq = (q < 2) ? s.x : s.y;
        acc[4 * q + 0] = fmaf(sq, (float)(v & 0xffu), acc[4 * q + 0]);
        acc[4 * q + 1] = fmaf(sq, (float)((v >> 8) & 0xffu), acc[4 * q + 1]);
        acc[4 * q + 2] = fmaf(sq, (float)((v >> 16) & 0xffu), acc[4 * q + 2]);
        acc[4 * q + 3] = fmaf(sq, (float)(v >> 24), acc[4 * q + 3]);
    }
}

// L0: signed q8 gather -> fp16 conv-out + fused BN partials (d=128, 8 lanes/node)
__global__ __launch_bounds__(256) void k_agg_q8s(const uint4* __restrict__ Q,
                                                 const float* __restrict__ sc,
                                                 __half* __restrict__ outh,
                                                 const int* __restrict__ rowptr,
                                                 const int* __restrict__ degcnt,
                                                 const int* __restrict__ colv,
                                                 const float* __restrict__ dis,
                                                 const float* __restrict__ bias,
                                                 float* __restrict__ part) {
    int g    = threadIdx.x >> 3;
    int lane = threadIdx.x & 7;
    int i = blockIdx.x * 32 + g;
    bool alive = i < NN;
    int beg = alive ? rowptr[i] : 0;
    int cnt = alive ? degcnt[i] : 0;
    const uint4*  base = Q + lane;
    const float2* scb  = (const float2*)sc + lane;
    float acc[16] = {};
    float c0 = 0.f, c1 = 0.f;
    int e = 0;
    for (; e + 8 <= cnt; e += 8) {
        int c[8];
        #pragma unroll
        for (int j = 0; j < 8; j++) c[j] = colv[beg + e + j];
        uint4 r[8];
        float2 s[8];
        #pragma unroll
        for (int j = 0; j < 8; j++) {
            r[j] = base[(size_t)c[j] * 8];
            s[j] = scb[(size_t)c[j] * 8];
        }
        #pragma unroll
        for (int j = 0; j < 8; j++) acc_q8s2(acc, r[j], s[j], c0, c1);
    }
    for (; e < cnt; e++) {
        int c = colv[beg + e];
        acc_q8s2(acc, base[(size_t)c * 8], scb[(size_t)c * 8], c0, c1);
    }
    if (alive) acc_q8s2(acc, base[(size_t)i * 8], scb[(size_t)i * 8], c0, c1);
    float ds = alive ? dis[i] : 0.f;
    float zp0 = 128.f * c0, zp1 = 128.f * c1;
    const float4* bi = (const float4*)bias;
    float o[16];
    #pragma unroll
    for (int j = 0; j < 4; j++) {
        float4 b = bi[lane * 4 + j];
        o[4 * j + 0] = alive ? ds * (acc[4 * j + 0] - (j < 2 ? zp0 : zp1)) + b.x : 0.f;
        o[4 * j + 1] = alive ? ds * (acc[4 * j + 1] - (j < 2 ? zp0 : zp1)) + b.y : 0.f;
        o[4 * j + 2] = alive ? ds * (acc[4 * j + 2] - (j < 2 ? zp0 : zp1)) + b.z : 0.f;
        o[4 * j + 3] = alive ? ds * (acc[4 * j + 3] - (j < 2 ? zp0 : zp1)) + b.w : 0.f;
    }
    if (alive) {
        uint4 ov0, ov1;
        __half2* p0 = (__half2*)&ov0;
        __half2* p1 = (__half2*)&ov1;
        #pragma unroll
        for (int k = 0; k < 4; k++) {
            p0[k] = __floats2half2_rn(o[2 * k], o[2 * k + 1]);
            p1[k] = __floats2half2_rn(o[8 + 2 * k], o[9 + 2 * k]);
        }
        uint4* out = (uint4*)outh;
        out[(size_t)i * 16 + lane * 2]     = ov0;
        out[(size_t)i * 16 + lane * 2 + 1] = ov1;
    }
    // fused BN partials (from fp32 o[], pre-rounding)
    __shared__ float lsh[32][129];
    #pragma unroll
    for (int k = 0; k < 16; k++) lsh[g][lane * 16 + k] = o[k];
    __syncthreads();
    if (threadIdx.x < 128) {
        float s = 0.f, q = 0.f;
        #pragma unroll 4
        for (int gg = 0; gg < 32; gg++) {
            float v = lsh[gg][threadIdx.x];
            s += v; q += v * v;
        }
        part[(size_t)blockIdx.x * 256 + threadIdx.x]       = s;
        part[(size_t)blockIdx.x * 256 + 128 + threadIdx.x] = q;
    }
}

// L1: unsigned q8 gather -> fp16 GEMM operand (no BN here; verified R3 kernel)
__device__ __forceinline__ void acc_q8u(float* acc, const uint4& r, float s) {
    const unsigned* w = (const unsigned*)&r;
    #pragma unroll
    for (int q = 0; q < 4; q++) {
        unsigned v = w[q];
        acc[4 * q + 0] = fmaf(s, (float)(v & 0xffu), acc[4 * q + 0]);
        acc[4 * q + 1] = fmaf(s, (float)((v >> 8) & 0xffu), acc[4 * q + 1]);
        acc[4 * q + 2] = fmaf(s, (float)((v >> 16) & 0xffu), acc[4 * q + 2]);
        acc[4 * q + 3] = fmaf(s, (float)(v >> 24), acc[4 * q + 3]);
    }
}

__global__ __launch_bounds__(256) void k_agg_q8u(const uint4* __restrict__ Q,
                                                 const float* __restrict__ sc,
                                                 __half* __restrict__ out16,
                                                 const int* __restrict__ rowptr,
                                                 const int* __restrict__ degcnt,
                                                 const int* __restrict__ colv,
                                                 const float* __restrict__ dis) {
    int g    = threadIdx.x >> 3;
    int lane = threadIdx.x & 7;
    int i = blockIdx.x * 32 + g;
    if (i >= NN) return;
    int beg = rowptr[i];
    int cnt = degcnt[i];
    const uint4* base = Q + lane;
    const float* scb  = sc + lane;
    float acc[16] = {};
    int e = 0;
    for (; e + 8 <= cnt; e += 8) {
        int c[8];
        #pragma unroll
        for (int j = 0; j < 8; j++) c[j] = colv[beg + e + j];
        uint4 r[8];
        float s[8];
        #pragma unroll
        for (int j = 0; j < 8; j++) {
            r[j] = base[(size_t)c[j] * 8];
            s[j] = scb[(size_t)c[j] * 8];
        }
        #pragma unroll
        for (int j = 0; j < 8; j++) acc_q8u(acc, r[j], s[j]);
    }
    for (; e < cnt; e++) {
        int c = colv[beg + e];
        acc_q8u(acc, base[(size_t)c * 8], scb[(size_t)c * 8]);
    }
    acc_q8u(acc, base[(size_t)i * 8], scb[(size_t)i * 8]);
    float ds = dis[i];
    float o[16];
    #pragma unroll
    for (int k = 0; k < 16; k++) o[k] = ds * acc[k];
    uint4 ov0, ov1;
    __half2* p0 = (__half2*)&ov0;
    __half2* p1 = (__half2*)&ov1;
    #pragma unroll
    for (int k = 0; k < 4; k++) {
        p0[k] = __floats2half2_rn(o[2 * k], o[2 * k + 1]);
        p1[k] = __floats2half2_rn(o[8 + 2 * k], o[9 + 2 * k]);
    }
    uint4* out = (uint4*)out16;
    out[(size_t)i * 16 + lane * 2]     = ov0;
    out[(size_t)i * 16 + lane * 2 + 1] = ov1;
}

// fp16 row gather -> fp16 conv-out + fused BN partials. TPN=d/8 lanes/node.
__device__ __forceinline__ void acc_row(float* acc, const uint4& r) {
    const __half2* hp = (const __half2*)&r;
    #pragma unroll
    for (int k = 0; k < 4; k++) {
        float2 f2 = __half22float2(hp[k]);
        acc[2 * k]     += f2.x;
        acc[2 * k + 1] += f2.y;
    }
}

template<int TPN>
__global__ __launch_bounds__(256) void k_agg_hf(const uint4* __restrict__ Hs,
                                                __half* __restrict__ outh,
                                                const int* __restrict__ rowptr,
                                                const int* __restrict__ degcnt,
                                                const int* __restrict__ colv,
                                                const float* __restrict__ dis,
                                                const float* __restrict__ bias,
                                                float* __restrict__ part) {
    constexpr int G = 256 / TPN;
    constexpr int D = TPN * 8;
    int g    = threadIdx.x / TPN;
    int lane = threadIdx.x % TPN;
    int i = blockIdx.x * G + g;
    bool alive = i < NN;
    int beg = alive ? rowptr[i] : 0;
    int cnt = alive ? degcnt[i] : 0;
    const uint4* base = Hs + lane;
    float acc[8] = {};
    int e = 0;
    for (; e + 8 <= cnt; e += 8) {
        int c[8];
        #pragma unroll
        for (int j = 0; j < 8; j++) c[j] = colv[beg + e + j];
        uint4 r[8];
        #pragma unroll
        for (int j = 0; j < 8; j++) r[j] = base[(size_t)c[j] * TPN];
        #pragma unroll
        for (int j = 0; j < 8; j++) acc_row(acc, r[j]);
    }
    for (; e < cnt; e++) {
        uint4 r = base[(size_t)colv[beg + e] * TPN];
        acc_row(acc, r);
    }
    if (alive) {
        uint4 rs = base[(size_t)i * TPN];  // self-loop
        acc_row(acc, rs);
    }
    float ds = alive ? dis[i] : 0.f;
    float4 b0 = ((const float4*)bias)[lane * 2];
    float4 b1 = ((const float4*)bias)[lane * 2 + 1];
    float o[8];
    o[0] = alive ? ds * acc[0] + b0.x : 0.f;
    o[1] = alive ? ds * acc[1] + b0.y : 0.f;
    o[2] = alive ? ds * acc[2] + b0.z : 0.f;
    o[3] = alive ? ds * acc[3] + b0.w : 0.f;
    o[4] = alive ? ds * acc[4] + b1.x : 0.f;
    o[5] = alive ? ds * acc[5] + b1.y : 0.f;
    o[6] = alive ? ds * acc[6] + b1.z : 0.f;
    o[7] = alive ? ds * acc[7] + b1.w : 0.f;
    if (alive) {
        uint4 ov;
        __half2* op = (__half2*)&ov;
        #pragma unroll
        for (int k = 0; k < 4; k++) op[k] = __floats2half2_rn(o[2 * k], o[2 * k + 1]);
        ((uint4*)outh)[(size_t)i * TPN + lane] = ov;
    }
    // fused BN partials
    __shared__ float lsh[G][D + 1];
    #pragma unroll
    for (int k = 0; k < 8; k++) lsh[g][lane * 8 + k] = o[k];
    __syncthreads();
    if (threadIdx.x < D) {
        float s = 0.f, q = 0.f;
        #pragma unroll 4
        for (int gg = 0; gg < G; gg++) {
            float v = lsh[gg][threadIdx.x];
            s += v; q += v * v;
        }
        part[(size_t)blockIdx.x * (2 * D) + threadIdx.x]     = s;
        part[(size_t)blockIdx.x * (2 * D) + D + threadIdx.x] = q;
    }
}

// ---------------------------------------------------------------- BatchNorm
// L1 GEMM path: separate partial pass reading fp16 conv-out.

template<int D>
__global__ __launch_bounds__(256) void k_bnpart_h(const uint4* __restrict__ X,
                                                  float* __restrict__ partial) {
    constexpr int Q   = D / 8;     // uint4 (8 halfs) per row
    constexpr int RPI = 256 / Q;
    int tq = threadIdx.x % Q;
    int rg = threadIdx.x / Q;
    int chunk = (NN + BNBLK - 1) / BNBLK;
    int r0 = blockIdx.x * chunk;
    int r1 = r0 + chunk; if (r1 > NN) r1 = NN;
    float s[8] = {}, q2[8] = {};
    for (int r = r0 + rg; r < r1; r += RPI) {
        uint4 v = X[(size_t)r * Q + tq];
        const __half2* hp = (const __half2*)&v;
        #pragma unroll
        for (int k = 0; k < 4; k++) {
            float2 f = __half22float2(hp[k]);
            s[2 * k] += f.x;  s[2 * k + 1] += f.y;
            q2[2 * k] += f.x * f.x; q2[2 * k + 1] += f.y * f.y;
        }
    }
    __shared__ float ls[2048], ls2[2048];
    #pragma unroll
    for (int k = 0; k < 8; k++) {
        ls[threadIdx.x * 8 + k]  = s[k];
        ls2[threadIdx.x * 8 + k] = q2[k];
    }
    __syncthreads();
    if (threadIdx.x < Q) {
        #pragma unroll 2
        for (int g = 1; g < RPI; g++)
            #pragma unroll
            for (int k = 0; k < 8; k++) {
                s[k]  += ls[(g * Q + threadIdx.x) * 8 + k];
                q2[k] += ls2[(g * Q + threadIdx.x) * 8 + k];
            }
        #pragma unroll
        for (int k = 0; k < 8; k++) {
            partial[(size_t)blockIdx.x * 2 * D + threadIdx.x * 8 + k]     = s[k];
            partial[(size_t)blockIdx.x * 2 * D + D + threadIdx.x * 8 + k] = q2[k];
        }
    }
}

// final reduce over P partial rows of [D sums][D sqs]
template<int D>
__global__ __launch_bounds__(1024) void k_bnfinP(const float* __restrict__ partial,
                                                 int P,
                                                 const float* __restrict__ g,
                                                 const float* __restrict__ be,
                                                 float* __restrict__ AB) {
    constexpr int G = 1024 / D;
    int f  = threadIdx.x % D;
    int gr = threadIdx.x / D;
    float sum = 0.f, sq = 0.f;
    for (int b = gr; b < P; b += G) {
        sum += partial[(size_t)b * 2 * D + f];
        sq  += partial[(size_t)b * 2 * D + D + f];
    }
    __shared__ float ls[1024], ls2[1024];
    ls[threadIdx.x] = sum; ls2[threadIdx.x] = sq;
    __syncthreads();
    if (threadIdx.x < D) {
        float a = ls[threadIdx.x], b = ls2[threadIdx.x];
        for (int k = 1; k < G; k++) {
            a += ls[k * D + threadIdx.x];
            b += ls2[k * D + threadIdx.x];
        }
        float mu  = a / (float)NN;
        float var = b / (float)NN - mu * mu;
        var = fmaxf(var, 0.f);
        float inv = rsqrtf(var + EPSB);
        float sc = g[threadIdx.x] * inv;
        AB[threadIdx.x]     = sc;
        AB[D + threadIdx.x] = be[threadIdx.x] - mu * sc;
    }
}

// final-layer BN+ReLU fp16->fp16 (d=32)
__global__ void k_norm16h(const uint4* __restrict__ X, const float* __restrict__ AB,
                          uint4* __restrict__ Y) {
    int t = blockIdx.x * blockDim.x + threadIdx.x;
    if (t >= NN * 4) return;
    int f0 = (t & 3) * 8;
    uint4 v = X[t];
    const __half2* hp = (const __half2*)&v;
    float x[8];
    #pragma unroll
    for (int k = 0; k < 4; k++) {
        float2 f = __half22float2(hp[k]);
        x[2 * k] = f.x; x[2 * k + 1] = f.y;
    }
    uint4 ov;
    __half2* op = (__half2*)&ov;
    #pragma unroll
    for (int k = 0; k < 4; k++) {
        float o0 = fmaxf(x[2 * k] * AB[f0 + 2 * k] + AB[32 + f0 + 2 * k], 0.f);
        float o1 = fmaxf(x[2 * k + 1] * AB[f0 + 2 * k + 1] + AB[32 + f0 + 2 * k + 1], 0.f);
        op[k] = __floats2half2_rn(o0, o1);
    }
    Y[t] = ov;
}

// ---------------------------------------------------------------- final edge MLP

__global__ __launch_bounds__(256) void k_edge16(const uint4* __restrict__ X,
                                                const int* __restrict__ src,
                                                const int* __restrict__ dst,
                                                const float* __restrict__ fcw,
                                                const float* __restrict__ fcb,
                                                float* __restrict__ out) {
    int lane = threadIdx.x & 3;
    size_t t = (size_t)blockIdx.x * 256 + threadIdx.x;
    int eid = (int)(t >> 2);
    if (eid >= EE) return;
    int s = src[eid], d = dst[eid];
    uint4 av = X[(size_t)s * 4 + lane];
    uint4 bv = X[(size_t)d * 4 + lane];
    const __half2* ap = (const __half2*)&av;
    const __half2* bp2 = (const __half2*)&bv;
    float v = 0.f;
    #pragma unroll
    for (int k = 0; k < 4; k++) {
        float2 fa = __half22float2(ap[k]);
        float2 fb = __half22float2(bp2[k]);
        float w0 = fcw[lane * 8 + 2 * k];
        float w1 = fcw[lane * 8 + 2 * k + 1];
        v += fa.x * fb.x * w0 + fa.y * fb.y * w1;
    }
    v += __shfl_xor(v, 1, 4);
    v += __shfl_xor(v, 2, 4);
    if (lane == 0) out[eid] = 1.f / (1.f + expf(-(v + fcb[0])));
}

// ---------------------------------------------------------------- launch

extern "C" void kernel_launch(void* const* d_in, const int* in_sizes, int n_in,
                              void* d_out, int out_size, void* d_ws, size_t ws_size,
                              hipStream_t stream) {
    const float* x0 = (const float*)d_in[0];
    const int* ei   = (const int*)d_in[1];
    const int* srcv = ei;
    const int* dstv = ei + EE;
    const float *W[5], *bp[5], *gp[5], *bep[5];
    int idx = 2;
    for (int l = 0; l < 5; l++) {
        W[l]   = (const float*)d_in[idx++];
        bp[l]  = (const float*)d_in[idx++];
        gp[l]  = (const float*)d_in[idx++];
        bep[l] = (const float*)d_in[idx++];
    }
    const float* fcw = (const float*)d_in[22];
    const float* fcb = (const float*)d_in[23];

    char* ws = (char*)d_ws;
    size_t off = 0;
    auto alloc = [&](size_t bytes) -> void* {
        void* p = ws + off;
        off = (off + bytes + 255) & ~(size_t)255;
        return p;
    };
    __half*   conv16  = (__half*)  alloc((size_t)NN * 256 * 2);   // fp16 conv-out
    __half*   act16   = (__half*)  alloc((size_t)NN * 256 * 2);
    __half*   x16     = (__half*)  alloc((size_t)NN * 128 * 2);
    __half*   Hh      = (__half*)  alloc((size_t)NN * 128 * 2);
    unsigned* barr    = (unsigned*)alloc((size_t)NB * BCAP * 4);
    int*      colv    = (int*)     alloc((size_t)EE * 4);
    int*      rowptr  = (int*)     alloc((size_t)NN * 4);
    int*      degcnt  = (int*)     alloc((size_t)NN * 4);
    float*    dis     = (float*)   alloc((size_t)NN * 4);
    int*      bcur    = (int*)     alloc((size_t)NB * 4);
    int*      scnblk  = (int*)     alloc(4096);
    float*    part    = (float*)   alloc((size_t)6250 * 256 * 4); // 6.4MB partials
    float*    bnAB    = (float*)   alloc(512 * 4);
    __half*   Wp      = (__half*)  alloc((size_t)92160 * 2);
    float*    scq     = (float*)   alloc((size_t)NN * 16 * 4);
    const int woff[5] = {0, 16384, 49152, 81920, 90112};

    // q8 rows live in barr's region (dead after CSR build): NN*128 B = 12.8MB
    unsigned char* q8 = (unsigned char*)barr;

    // ---- CSR build (binned counting sort)
    hipMemsetAsync(bcur, 0, (size_t)NB * 4, stream);
    k_bscat<<<(EE + 4095) / 4096, 256, 0, stream>>>(srcv, dstv, bcur, barr);
    k_bdeg<<<NB, 1024, 0, stream>>>(bcur, barr, degcnt, dis);
    int nScanBlk = (NN + 1023) / 1024;
    k_scan_block<<<nScanBlk, 1024, 0, stream>>>(degcnt, rowptr, scnblk, NN);
    k_scan_top<<<1, 64, 0, stream>>>(scnblk, nScanBlk);
    k_scan_add<<<nScanBlk, 1024, 0, stream>>>(rowptr, scnblk, NN);
    k_place<<<NB, 1024, 0, stream>>>(bcur, barr, rowptr, colv);

    // ---- casts / weight packs
    k_f2h<<<(NN * 128 / 4 + 255) / 256, 256, 0, stream>>>(
        (const float4*)x0, (uint2*)x16, NN * 128 / 4);
    k_wpack_all<<<(92160 + 255) / 256, 256, 0, stream>>>(W[0], W[1], W[2], W[3], W[4], Wp);

    int gx = (NN + 127) / 128;

    // ---- layer 0: mgemm(x16)->Hh ; q8p8 ; agg_q8s(+b0,fused BN)->conv16 ; bnfin ; nscale_q8
    {
        dim3 grid(gx, 128 / 64);
        k_mgemm<4, true, false, false, false><<<grid, 256, 0, stream>>>(
            x16, Wp + woff[0], Hh, NN, 128, 128, dis, nullptr, nullptr);
        k_q8p8<<<NN * 16 / 256, 256, 0, stream>>>((const uint4*)Hh, (uint2*)q8, scq, NN * 16);
        k_agg_q8s<<<(NN + 31) / 32, 256, 0, stream>>>(
            (const uint4*)q8, scq, conv16, rowptr, degcnt, colv, dis, bp[0], part);
        k_bnfinP<128><<<1, 1024, 0, stream>>>(part, (NN + 31) / 32, gp[0], bep[0], bnAB);
        k_nscale_q8<<<(NN * 16 + 255) / 256, 256, 0, stream>>>(conv16, bnAB, dis, (uint2*)q8, scq);
    }
    // ---- layer 1 (agg first): agg_q8u->act16 ; mgemm(+b1, fp16 out)->conv16 ; bnpart_h ; bnfin
    {
        k_agg_q8u<<<(NN + 31) / 32, 256, 0, stream>>>(
            (const uint4*)q8, scq, act16, rowptr, degcnt, colv, dis);
        dim3 grid(gx, 256 / 64);
        k_mgemm<4, false, false, false, true><<<grid, 256, 0, stream>>>(
            act16, Wp + woff[1], conv16, NN, 128, 256, nullptr, bp[1], nullptr);
        k_bnpart_h<256><<<BNBLK, 256, 0, stream>>>((const uint4*)conv16, part);
        k_bnfinP<256><<<1, 1024, 0, stream>>>(part, BNBLK, gp[1], bep[1], bnAB);
    }
    // ---- layer 2: mgemm(ABN16 d=256)->Hh ; agg_hf<16>(+b2,fused)->conv16 ; bnfin
    {
        dim3 grid(gx, 128 / 64);
        k_mgemm<4, true, true, true, false><<<grid, 256, 0, stream>>>(
            conv16, Wp + woff[2], Hh, NN, 256, 128, dis, nullptr, bnAB);
        k_agg_hf<16><<<(NN + 15) / 16, 256, 0, stream>>>(
            (const uint4*)Hh, conv16, rowptr, degcnt, colv, dis, bp[2], part);
        k_bnfinP<128><<<1, 1024, 0, stream>>>(part, (NN + 15) / 16, gp[2], bep[2], bnAB);
    }
    // ---- layer 3 (d=64): mgemm(ABN16 d=128)->Hh ; agg_hf<8>(+b3,fused)->conv16 ; bnfin
    {
        dim3 grid(gx, 64 / 64);
        k_mgemm<4, true, true, true, false><<<grid, 256, 0, stream>>>(
            conv16, Wp + woff[3], Hh, NN, 128, 64, dis, nullptr, bnAB);
        k_agg_hf<8><<<(NN + 31) / 32, 256, 0, stream>>>(
            (const uint4*)Hh, conv16, rowptr, degcnt, colv, dis, bp[3], part);
        k_bnfinP<64><<<1, 1024, 0, stream>>>(part, (NN + 31) / 32, gp[3], bep[3], bnAB);
    }
    // ---- layer 4 (d=32): mgemm(ABN16 d=64)->Hh ; agg_hf<4>(+b4,fused)->conv16 ; bnfin ; norm16h
    {
        dim3 grid(gx, 1);
        k_mgemm<2, true, true, true, false><<<grid, 256, 0, stream>>>(
            conv16, Wp + woff[4], Hh, NN, 64, 32, dis, nullptr, bnAB);
        k_agg_hf<4><<<(NN + 63) / 64, 256, 0, stream>>>(
            (const uint4*)Hh, conv16, rowptr, degcnt, colv, dis, bp[4], part);
        k_bnfinP<32><<<1, 1024, 0, stream>>>(part, (NN + 63) / 64, gp[4], bep[4], bnAB);
        k_norm16h<<<(NN * 4 + 255) / 256, 256, 0, stream>>>(
            (const uint4*)conv16, bnAB, (uint4*)act16);
    }

    size_t edgeThreads = (size_t)EE * 4;
    k_edge16<<<(unsigned)((edgeThreads + 255) / 256), 256, 0, stream>>>(
        (const uint4*)act16, srcv, dstv, fcw, fcb, (float*)d_out);
}

// Round 9
// 960.932 us; speedup vs baseline: 2.0113x; 1.2989x over previous
//
#include <hip/hip_runtime.h>
#include <hip/hip_fp16.h>
#include <cstddef>

#define NN 100000
#define EE 3200000
#define EPSB 1e-5f
#define NB 391      // buckets = ceil(NN/256)
#define BCAP 10240  // per-bucket edge capacity
#define BNBLK 512   // BN partial blocks for the L1 GEMM path

typedef _Float16 half8 __attribute__((ext_vector_type(8)));
typedef float floatx4 __attribute__((ext_vector_type(4)));

// ---------------------------------------------------------------- CSR build
// packed record: src (17 bits) | dst&255 (8 bits) << 17

__global__ __launch_bounds__(256) void k_bscat(const int* __restrict__ src,
                                               const int* __restrict__ dst,
                                               int* __restrict__ bcur,
                                               unsigned* __restrict__ barr) {
    __shared__ int hist[NB];
    __shared__ int base[NB];
    int tid = threadIdx.x;
    for (int b = tid; b < NB; b += 256) hist[b] = 0;
    __syncthreads();
    int e0 = blockIdx.x * 4096;
    int d[16], s[16];
    #pragma unroll
    for (int j = 0; j < 16; j++) {
        int e = e0 + j * 256 + tid;
        if (e < EE) {
            d[j] = dst[e];
            s[j] = src[e];
            atomicAdd(&hist[d[j] >> 8], 1);
        } else d[j] = -1;
    }
    __syncthreads();
    for (int b = tid; b < NB; b += 256) {
        int c = hist[b];
        base[b] = (c > 0) ? atomicAdd(&bcur[b], c) : 0;
        hist[b] = 0;
    }
    __syncthreads();
    #pragma unroll
    for (int j = 0; j < 16; j++) {
        if (d[j] >= 0) {
            int b = d[j] >> 8;
            int r = atomicAdd(&hist[b], 1);
            barr[(size_t)b * BCAP + base[b] + r] =
                (unsigned)s[j] | ((unsigned)(d[j] & 255) << 17);
        }
    }
}

__global__ __launch_bounds__(1024) void k_bdeg(const int* __restrict__ bcur,
                                               const unsigned* __restrict__ barr,
                                               int* __restrict__ degcnt,
                                               float* __restrict__ dis) {
    __shared__ int h[256];
    int b = blockIdx.x;
    if (threadIdx.x < 256) h[threadIdx.x] = 0;
    __syncthreads();
    int cnt = bcur[b];
    const unsigned* p = barr + (size_t)b * BCAP;
    for (int t = threadIdx.x; t < cnt; t += 1024)
        atomicAdd(&h[(p[t] >> 17) & 255], 1);
    __syncthreads();
    if (threadIdx.x < 256) {
        int node = (b << 8) + threadIdx.x;
        if (node < NN) {
            int dg = h[threadIdx.x];
            degcnt[node] = dg;
            dis[node] = rsqrtf((float)dg + 1.0f);
        }
    }
}

__global__ __launch_bounds__(1024) void k_place(const int* __restrict__ bcur,
                                                const unsigned* __restrict__ barr,
                                                const int* __restrict__ rowptr,
                                                int* __restrict__ col) {
    __shared__ int cur[256];
    int b = blockIdx.x;
    if (threadIdx.x < 256) {
        int node = (b << 8) + threadIdx.x;
        cur[threadIdx.x] = (node < NN) ? rowptr[node] : 0;
    }
    __syncthreads();
    int cnt = bcur[b];
    const unsigned* p = barr + (size_t)b * BCAP;
    for (int t = threadIdx.x; t < cnt; t += 1024) {
        unsigned e = p[t];
        int pos = atomicAdd(&cur[(e >> 17) & 255], 1);
        col[pos] = (int)(e & 0x1FFFFu);
    }
}

__global__ void k_scan_block(const int* __restrict__ in, int* __restrict__ out,
                             int* __restrict__ blksum, int n) {
    __shared__ int s[1024];
    int i = blockIdx.x * 1024 + threadIdx.x;
    int v = (i < n) ? in[i] : 0;
    s[threadIdx.x] = v;
    __syncthreads();
    for (int off = 1; off < 1024; off <<= 1) {
        int t = (threadIdx.x >= off) ? s[threadIdx.x - off] : 0;
        __syncthreads();
        s[threadIdx.x] += t;
        __syncthreads();
    }
    if (i < n) out[i] = s[threadIdx.x] - v;  // exclusive
    if (threadIdx.x == 1023) blksum[blockIdx.x] = s[1023];
}

__global__ void k_scan_top(int* __restrict__ blksum, int nb) {
    if (threadIdx.x == 0) {
        int acc = 0;
        for (int b = 0; b < nb; b++) { int v = blksum[b]; blksum[b] = acc; acc += v; }
    }
}

__global__ void k_scan_add(int* __restrict__ out, const int* __restrict__ blksum, int n) {
    int i = blockIdx.x * 1024 + threadIdx.x;
    if (i < n) out[i] += blksum[blockIdx.x];
}

// ---------------------------------------------------------------- casts / packing

__global__ void k_f2h(const float4* __restrict__ in, uint2* __restrict__ out, int n4) {
    int t = blockIdx.x * blockDim.x + threadIdx.x;
    if (t >= n4) return;
    float4 v = in[t];
    union { __half2 h; unsigned u; } a, b;
    a.h = __floats2half2_rn(v.x, v.y);
    b.h = __floats2half2_rn(v.z, v.w);
    out[t] = make_uint2(a.u, b.u);
}

__global__ void k_wpack_all(const float* __restrict__ W0, const float* __restrict__ W1,
                            const float* __restrict__ W2, const float* __restrict__ W3,
                            const float* __restrict__ W4, __half* __restrict__ Wp) {
    const int offs[6] = {0, 16384, 49152, 81920, 90112, 92160};
    const int Ks[5] = {128, 128, 256, 128, 64};
    const int Ns[5] = {128, 256, 128, 64, 32};
    const float* Ws[5] = {W0, W1, W2, W3, W4};
    int t = blockIdx.x * blockDim.x + threadIdx.x;
    if (t >= 92160) return;
    int l = 0;
    while (t >= offs[l + 1]) l++;
    int local = t - offs[l];
    int N = Ns[l], K = Ks[l];
    int k = local / N, n = local - k * N;
    Wp[(size_t)offs[l] + (size_t)n * K + k] = __float2half(Ws[l][local]);
}

// ---------------------------------------------------------------- MFMA GEMM
// modes: OUT16: C fp16 = dis*acc (agg operand, Hh). CH16: C fp16 = acc+bias
// (conv-out). ABN: BN+ReLU during A staging; AH16: ABN input is fp16.

template<int NT, bool OUT16, bool ABN, bool AH16, bool CH16>
__global__ __launch_bounds__(256) void k_mgemm(const void* __restrict__ Av,
                                               const __half* __restrict__ Wp,
                                               void* __restrict__ Cv,
                                               int M, int K, int N,
                                               const float* __restrict__ dis,
                                               const float* __restrict__ bias,
                                               const float* __restrict__ AB) {
    constexpr int TN = NT * 16;
    __shared__ __half Ash[128][40];
    __shared__ __half Bsh[TN][40];
    int tid  = threadIdx.x;
    int wave = tid >> 6;
    int lane = tid & 63;
    int quad = lane >> 4;
    int l16  = lane & 15;
    int bm = blockIdx.x * 128;
    int bn = blockIdx.y * TN;

    floatx4 acc[2][NT];
    #pragma unroll
    for (int mt = 0; mt < 2; mt++)
        #pragma unroll
        for (int nt = 0; nt < NT; nt++)
            acc[mt][nt] = (floatx4){0.f, 0.f, 0.f, 0.f};

    for (int k0 = 0; k0 < K; k0 += 32) {
        #pragma unroll
        for (int it = 0; it < 2; it++) {
            int u = tid + it * 256;
            int row = u >> 2, seg = u & 3;
            int grow = bm + row;
            if (ABN) {
                int f0 = k0 + seg * 8;
                uint4 o = make_uint4(0, 0, 0, 0);
                if (grow < M) {
                    float x[8];
                    if (AH16) {
                        const __half* Af = (const __half*)Av;
                        uint4 xv = *(const uint4*)&Af[(size_t)grow * K + f0];
                        const __half2* xp = (const __half2*)&xv;
                        #pragma unroll
                        for (int k = 0; k < 4; k++) {
                            float2 f = __half22float2(xp[k]);
                            x[2 * k] = f.x; x[2 * k + 1] = f.y;
                        }
                    } else {
                        const float* Af = (const float*)Av;
                        float4 x0 = *(const float4*)&Af[(size_t)grow * K + f0];
                        float4 x1 = *(const float4*)&Af[(size_t)grow * K + f0 + 4];
                        x[0] = x0.x; x[1] = x0.y; x[2] = x0.z; x[3] = x0.w;
                        x[4] = x1.x; x[5] = x1.y; x[6] = x1.z; x[7] = x1.w;
                    }
                    float4 a0 = *(const float4*)&AB[f0];
                    float4 a1 = *(const float4*)&AB[f0 + 4];
                    float4 c0 = *(const float4*)&AB[K + f0];
                    float4 c1 = *(const float4*)&AB[K + f0 + 4];
                    float h0 = fmaxf(x[0] * a0.x + c0.x, 0.f);
                    float h1 = fmaxf(x[1] * a0.y + c0.y, 0.f);
                    float h2 = fmaxf(x[2] * a0.z + c0.z, 0.f);
                    float h3 = fmaxf(x[3] * a0.w + c0.w, 0.f);
                    float h4 = fmaxf(x[4] * a1.x + c1.x, 0.f);
                    float h5 = fmaxf(x[5] * a1.y + c1.y, 0.f);
                    float h6 = fmaxf(x[6] * a1.z + c1.z, 0.f);
                    float h7 = fmaxf(x[7] * a1.w + c1.w, 0.f);
                    union { __half2 h; unsigned u; } p0, p1, p2, p3;
                    p0.h = __floats2half2_rn(h0, h1);
                    p1.h = __floats2half2_rn(h2, h3);
                    p2.h = __floats2half2_rn(h4, h5);
                    p3.h = __floats2half2_rn(h6, h7);
                    o = make_uint4(p0.u, p1.u, p2.u, p3.u);
                }
                *(uint4*)&Ash[row][seg * 8] = o;
            } else {
                const __half* A = (const __half*)Av;
                uint4 v = make_uint4(0, 0, 0, 0);
                if (grow < M) v = *(const uint4*)&A[(size_t)grow * K + k0 + seg * 8];
                *(uint4*)&Ash[row][seg * 8] = v;
            }
        }
        if (tid < TN * 4) {
            int n = tid >> 2, seg = tid & 3;
            uint4 v = *(const uint4*)&Wp[(size_t)(bn + n) * K + k0 + seg * 8];
            *(uint4*)&Bsh[n][seg * 8] = v;
        }
        __syncthreads();
        half8 a[2], b[NT];
        #pragma unroll
        for (int mt = 0; mt < 2; mt++)
            a[mt] = *(const half8*)&Ash[wave * 32 + mt * 16 + l16][quad * 8];
        #pragma unroll
        for (int nt = 0; nt < NT; nt++)
            b[nt] = *(const half8*)&Bsh[nt * 16 + l16][quad * 8];
        #pragma unroll
        for (int mt = 0; mt < 2; mt++)
            #pragma unroll
            for (int nt = 0; nt < NT; nt++)
                acc[mt][nt] = __builtin_amdgcn_mfma_f32_16x16x32_f16(
                    a[mt], b[nt], acc[mt][nt], 0, 0, 0);
        __syncthreads();
    }

    #pragma unroll
    for (int mt = 0; mt < 2; mt++) {
        #pragma unroll
        for (int r = 0; r < 4; r++) {
            int grow = bm + wave * 32 + mt * 16 + quad * 4 + r;
            if (grow >= M) continue;
            if (OUT16) {
                float ds = dis[grow];
                __half* C = (__half*)Cv;
                #pragma unroll
                for (int nt = 0; nt < NT; nt++) {
                    int gcol = bn + nt * 16 + l16;
                    C[(size_t)grow * N + gcol] = __float2half(ds * acc[mt][nt][r]);
                }
            } else if (CH16) {
                __half* C = (__half*)Cv;
                #pragma unroll
                for (int nt = 0; nt < NT; nt++) {
                    int gcol = bn + nt * 16 + l16;
                    C[(size_t)grow * N + gcol] = __float2half(acc[mt][nt][r] + bias[gcol]);
                }
            } else {
                float* C = (float*)Cv;
                #pragma unroll
                for (int nt = 0; nt < NT; nt++) {
                    int gcol = bn + nt * 16 + l16;
                    C[(size_t)grow * N + gcol] = acc[mt][nt][r] + bias[gcol];
                }
            }
        }
    }
}

// ---------------------------------------------------------------- int8 quant
// L0 operand: signed, per-8-feature scales; L1 operand: unsigned per-16.

__global__ __launch_bounds__(256) void k_q8p8(const uint4* __restrict__ H,
                                              uint2* __restrict__ q8,
                                              float* __restrict__ scq, int total) {
    int t = blockIdx.x * 256 + threadIdx.x;
    if (t >= total) return;
    uint4 v = H[t];
    const __half2* hp = (const __half2*)&v;
    float h[8];
    #pragma unroll
    for (int k = 0; k < 4; k++) {
        float2 f = __half22float2(hp[k]);
        h[2 * k] = f.x; h[2 * k + 1] = f.y;
    }
    float m = fabsf(h[0]);
    #pragma unroll
    for (int k = 1; k < 8; k++) m = fmaxf(m, fabsf(h[k]));
    float inv = m > 0.f ? 127.f / m : 0.f;
    unsigned b[8];
    #pragma unroll
    for (int k = 0; k < 8; k++) {
        float f = fminf(fmaxf(h[k] * inv, -127.f), 127.f);
        b[k] = (unsigned)(f + 128.5f);
    }
    q8[t] = make_uint2(b[0] | (b[1] << 8) | (b[2] << 16) | (b[3] << 24),
                       b[4] | (b[5] << 8) | (b[6] << 16) | (b[7] << 24));
    scq[t] = m * (1.f / 127.f);
}

// L1 fused BN+ReLU+dis-scale -> unsigned q8 (d=128, 16 threads/row), fp16 input
__global__ void k_nscale_q8(const __half* __restrict__ X, const float* __restrict__ AB,
                            const float* __restrict__ dis, uint2* __restrict__ q8,
                            float* __restrict__ scq) {
    int t = blockIdx.x * blockDim.x + threadIdx.x;
    if (t >= NN * 16) return;
    int row = t >> 4;
    int sub = t & 15;
    int f0 = sub * 8;
    float ds = dis[row];
    uint4 xv = ((const uint4*)X)[(size_t)row * 16 + sub];
    const __half2* xp = (const __half2*)&xv;
    float x[8];
    #pragma unroll
    for (int k = 0; k < 4; k++) {
        float2 f = __half22float2(xp[k]);
        x[2 * k] = f.x; x[2 * k + 1] = f.y;
    }
    float4 a0 = *(const float4*)&AB[f0];
    float4 a1 = *(const float4*)&AB[f0 + 4];
    float4 c0 = *(const float4*)&AB[128 + f0];
    float4 c1 = *(const float4*)&AB[128 + f0 + 4];
    float h[8];
    h[0] = ds * fmaxf(x[0] * a0.x + c0.x, 0.f);
    h[1] = ds * fmaxf(x[1] * a0.y + c0.y, 0.f);
    h[2] = ds * fmaxf(x[2] * a0.z + c0.z, 0.f);
    h[3] = ds * fmaxf(x[3] * a0.w + c0.w, 0.f);
    h[4] = ds * fmaxf(x[4] * a1.x + c1.x, 0.f);
    h[5] = ds * fmaxf(x[5] * a1.y + c1.y, 0.f);
    h[6] = ds * fmaxf(x[6] * a1.z + c1.z, 0.f);
    h[7] = ds * fmaxf(x[7] * a1.w + c1.w, 0.f);
    float m = h[0];
    #pragma unroll
    for (int k = 1; k < 8; k++) m = fmaxf(m, h[k]);
    m = fmaxf(m, __shfl_xor(m, 1));   // 16-feat group max
    float inv = m > 0.f ? 255.f / m : 0.f;
    unsigned b[8];
    #pragma unroll
    for (int k = 0; k < 8; k++)
        b[k] = (unsigned)(fminf(h[k] * inv, 255.f) + 0.5f);
    q8[t] = make_uint2(b[0] | (b[1] << 8) | (b[2] << 16) | (b[3] << 24),
                       b[4] | (b[5] << 8) | (b[6] << 16) | (b[7] << 24));
    if ((t & 1) == 0) scq[t >> 1] = m * (1.f / 255.f);
}

// ---------------------------------------------------------------- aggregation
// Lessons pinned:
//  - R4: byte-shrinking a latency-bound random gather is worthless.
//  - R5/R7: locality engineering fails; the ~113us/d=128 gather floor stands.
//  - R8: single-block BN final reduce over >3000 partial rows is latency-bound
//    (211us @0.19% BW). Fix: two-stage (k_bnmid grid-parallel, then tiny fin).

__device__ __forceinline__ void acc_q8s2(float* acc, const uint4& r,
                                         const float2& s, float& c0, float& c1) {
    const unsigned* w = (const unsigned*)&r;
    c0 += s.x; c1 += s.y;
    #pragma unroll
    for (int q = 0; q < 4; q++) {
        unsigned v = w[q];
        float sq = (q < 2) ? s.x : s.y;
        acc[4 * q + 0] = fmaf(sq, (float)(v & 0xffu), acc[4 * q + 0]);
        acc[4 * q + 1] = fmaf(sq, (float)((v >> 8) & 0xffu), acc[4 * q + 1]);
        acc[4 * q + 2] = fmaf(sq, (float)((v >> 16) & 0xffu), acc[4 * q + 2]);
        acc[4 * q + 3] = fmaf(sq, (float)(v >> 24), acc[4 * q + 3]);
    }
}

// L0: signed q8 gather -> fp16 conv-out + fused BN partials (d=128, 8 lanes/node)
__global__ __launch_bounds__(256) void k_agg_q8s(const uint4* __restrict__ Q,
                                                 const float* __restrict__ sc,
                                                 __half* __restrict__ outh,
                                                 const int* __restrict__ rowptr,
                                                 const int* __restrict__ degcnt,
                                                 const int* __restrict__ colv,
                                                 const float* __restrict__ dis,
                                                 const float* __restrict__ bias,
                                                 float* __restrict__ part) {
    int g    = threadIdx.x >> 3;
    int lane = threadIdx.x & 7;
    int i = blockIdx.x * 32 + g;
    bool alive = i < NN;
    int beg = alive ? rowptr[i] : 0;
    int cnt = alive ? degcnt[i] : 0;
    const uint4*  base = Q + lane;
    const float2* scb  = (const float2*)sc + lane;
    float acc[16] = {};
    float c0 = 0.f, c1 = 0.f;
    int e = 0;
    for (; e + 8 <= cnt; e += 8) {
        int c[8];
        #pragma unroll
        for (int j = 0; j < 8; j++) c[j] = colv[beg + e + j];
        uint4 r[8];
        float2 s[8];
        #pragma unroll
        for (int j = 0; j < 8; j++) {
            r[j] = base[(size_t)c[j] * 8];
            s[j] = scb[(size_t)c[j] * 8];
        }
        #pragma unroll
        for (int j = 0; j < 8; j++) acc_q8s2(acc, r[j], s[j], c0, c1);
    }
    for (; e < cnt; e++) {
        int c = colv[beg + e];
        acc_q8s2(acc, base[(size_t)c * 8], scb[(size_t)c * 8], c0, c1);
    }
    if (alive) acc_q8s2(acc, base[(size_t)i * 8], scb[(size_t)i * 8], c0, c1);
    float ds = alive ? dis[i] : 0.f;
    float zp0 = 128.f * c0, zp1 = 128.f * c1;
    const float4* bi = (const float4*)bias;
    float o[16];
    #pragma unroll
    for (int j = 0; j < 4; j++) {
        float4 b = bi[lane * 4 + j];
        o[4 * j + 0] = alive ? ds * (acc[4 * j + 0] - (j < 2 ? zp0 : zp1)) + b.x : 0.f;
        o[4 * j + 1] = alive ? ds * (acc[4 * j + 1] - (j < 2 ? zp0 : zp1)) + b.y : 0.f;
        o[4 * j + 2] = alive ? ds * (acc[4 * j + 2] - (j < 2 ? zp0 : zp1)) + b.z : 0.f;
        o[4 * j + 3] = alive ? ds * (acc[4 * j + 3] - (j < 2 ? zp0 : zp1)) + b.w : 0.f;
    }
    if (alive) {
        uint4 ov0, ov1;
        __half2* p0 = (__half2*)&ov0;
        __half2* p1 = (__half2*)&ov1;
        #pragma unroll
        for (int k = 0; k < 4; k++) {
            p0[k] = __floats2half2_rn(o[2 * k], o[2 * k + 1]);
            p1[k] = __floats2half2_rn(o[8 + 2 * k], o[9 + 2 * k]);
        }
        uint4* out = (uint4*)outh;
        out[(size_t)i * 16 + lane * 2]     = ov0;
        out[(size_t)i * 16 + lane * 2 + 1] = ov1;
    }
    // fused BN partials (from fp32 o[], pre-rounding)
    __shared__ float lsh[32][129];
    #pragma unroll
    for (int k = 0; k < 16; k++) lsh[g][lane * 16 + k] = o[k];
    __syncthreads();
    if (threadIdx.x < 128) {
        float s = 0.f, q = 0.f;
        #pragma unroll 4
        for (int gg = 0; gg < 32; gg++) {
            float v = lsh[gg][threadIdx.x];
            s += v; q += v * v;
        }
        part[(size_t)blockIdx.x * 256 + threadIdx.x]       = s;
        part[(size_t)blockIdx.x * 256 + 128 + threadIdx.x] = q;
    }
}

// L1: unsigned q8 gather -> fp16 GEMM operand
__device__ __forceinline__ void acc_q8u(float* acc, const uint4& r, float s) {
    const unsigned* w = (const unsigned*)&r;
    #pragma unroll
    for (int q = 0; q < 4; q++) {
        unsigned v = w[q];
        acc[4 * q + 0] = fmaf(s, (float)(v & 0xffu), acc[4 * q + 0]);
        acc[4 * q + 1] = fmaf(s, (float)((v >> 8) & 0xffu), acc[4 * q + 1]);
        acc[4 * q + 2] = fmaf(s, (float)((v >> 16) & 0xffu), acc[4 * q + 2]);
        acc[4 * q + 3] = fmaf(s, (float)(v >> 24), acc[4 * q + 3]);
    }
}

__global__ __launch_bounds__(256) void k_agg_q8u(const uint4* __restrict__ Q,
                                                 const float* __restrict__ sc,
                                                 __half* __restrict__ out16,
                                                 const int* __restrict__ rowptr,
                                                 const int* __restrict__ degcnt,
                                                 const int* __restrict__ colv,
                                                 const float* __restrict__ dis) {
    int g    = threadIdx.x >> 3;
    int lane = threadIdx.x & 7;
    int i = blockIdx.x * 32 + g;
    if (i >= NN) return;
    int beg = rowptr[i];
    int cnt = degcnt[i];
    const uint4* base = Q + lane;
    const float* scb  = sc + lane;
    float acc[16] = {};
    int e = 0;
    for (; e + 8 <= cnt; e += 8) {
        int c[8];
        #pragma unroll
        for (int j = 0; j < 8; j++) c[j] = colv[beg + e + j];
        uint4 r[8];
        float s[8];
        #pragma unroll
        for (int j = 0; j < 8; j++) {
            r[j] = base[(size_t)c[j] * 8];
            s[j] = scb[(size_t)c[j] * 8];
        }
        #pragma unroll
        for (int j = 0; j < 8; j++) acc_q8u(acc, r[j], s[j]);
    }
    for (; e < cnt; e++) {
        int c = colv[beg + e];
        acc_q8u(acc, base[(size_t)c * 8], scb[(size_t)c * 8]);
    }
    acc_q8u(acc, base[(size_t)i * 8], scb[(size_t)i * 8]);
    float ds = dis[i];
    float o[16];
    #pragma unroll
    for (int k = 0; k < 16; k++) o[k] = ds * acc[k];
    uint4 ov0, ov1;
    __half2* p0 = (__half2*)&ov0;
    __half2* p1 = (__half2*)&ov1;
    #pragma unroll
    for (int k = 0; k < 4; k++) {
        p0[k] = __floats2half2_rn(o[2 * k], o[2 * k + 1]);
        p1[k] = __floats2half2_rn(o[8 + 2 * k], o[9 + 2 * k]);
    }
    uint4* out = (uint4*)out16;
    out[(size_t)i * 16 + lane * 2]     = ov0;
    out[(size_t)i * 16 + lane * 2 + 1] = ov1;
}

// fp16 row gather -> fp16 conv-out + fused BN partials. TPN=d/8 lanes/node.
__device__ __forceinline__ void acc_row(float* acc, const uint4& r) {
    const __half2* hp = (const __half2*)&r;
    #pragma unroll
    for (int k = 0; k < 4; k++) {
        float2 f2 = __half22float2(hp[k]);
        acc[2 * k]     += f2.x;
        acc[2 * k + 1] += f2.y;
    }
}

template<int TPN>
__global__ __launch_bounds__(256) void k_agg_hf(const uint4* __restrict__ Hs,
                                                __half* __restrict__ outh,
                                                const int* __restrict__ rowptr,
                                                const int* __restrict__ degcnt,
                                                const int* __restrict__ colv,
                                                const float* __restrict__ dis,
                                                const float* __restrict__ bias,
                                                float* __restrict__ part) {
    constexpr int G = 256 / TPN;
    constexpr int D = TPN * 8;
    int g    = threadIdx.x / TPN;
    int lane = threadIdx.x % TPN;
    int i = blockIdx.x * G + g;
    bool alive = i < NN;
    int beg = alive ? rowptr[i] : 0;
    int cnt = alive ? degcnt[i] : 0;
    const uint4* base = Hs + lane;
    float acc[8] = {};
    int e = 0;
    for (; e + 8 <= cnt; e += 8) {
        int c[8];
        #pragma unroll
        for (int j = 0; j < 8; j++) c[j] = colv[beg + e + j];
        uint4 r[8];
        #pragma unroll
        for (int j = 0; j < 8; j++) r[j] = base[(size_t)c[j] * TPN];
        #pragma unroll
        for (int j = 0; j < 8; j++) acc_row(acc, r[j]);
    }
    for (; e < cnt; e++) {
        uint4 r = base[(size_t)colv[beg + e] * TPN];
        acc_row(acc, r);
    }
    if (alive) {
        uint4 rs = base[(size_t)i * TPN];  // self-loop
        acc_row(acc, rs);
    }
    float ds = alive ? dis[i] : 0.f;
    float4 b0 = ((const float4*)bias)[lane * 2];
    float4 b1 = ((const float4*)bias)[lane * 2 + 1];
    float o[8];
    o[0] = alive ? ds * acc[0] + b0.x : 0.f;
    o[1] = alive ? ds * acc[1] + b0.y : 0.f;
    o[2] = alive ? ds * acc[2] + b0.z : 0.f;
    o[3] = alive ? ds * acc[3] + b0.w : 0.f;
    o[4] = alive ? ds * acc[4] + b1.x : 0.f;
    o[5] = alive ? ds * acc[5] + b1.y : 0.f;
    o[6] = alive ? ds * acc[6] + b1.z : 0.f;
    o[7] = alive ? ds * acc[7] + b1.w : 0.f;
    if (alive) {
        uint4 ov;
        __half2* op = (__half2*)&ov;
        #pragma unroll
        for (int k = 0; k < 4; k++) op[k] = __floats2half2_rn(o[2 * k], o[2 * k + 1]);
        ((uint4*)outh)[(size_t)i * TPN + lane] = ov;
    }
    // fused BN partials
    __shared__ float lsh[G][D + 1];
    #pragma unroll
    for (int k = 0; k < 8; k++) lsh[g][lane * 8 + k] = o[k];
    __syncthreads();
    if (threadIdx.x < D) {
        float s = 0.f, q = 0.f;
        #pragma unroll 4
        for (int gg = 0; gg < G; gg++) {
            float v = lsh[gg][threadIdx.x];
            s += v; q += v * v;
        }
        part[(size_t)blockIdx.x * (2 * D) + threadIdx.x]     = s;
        part[(size_t)blockIdx.x * (2 * D) + D + threadIdx.x] = q;
    }
}

// ---------------------------------------------------------------- BatchNorm
// L1 GEMM path: separate partial pass reading fp16 conv-out.

template<int D>
__global__ __launch_bounds__(256) void k_bnpart_h(const uint4* __restrict__ X,
                                                  float* __restrict__ partial) {
    constexpr int Q   = D / 8;     // uint4 (8 halfs) per row
    constexpr int RPI = 256 / Q;
    int tq = threadIdx.x % Q;
    int rg = threadIdx.x / Q;
    int chunk = (NN + BNBLK - 1) / BNBLK;
    int r0 = blockIdx.x * chunk;
    int r1 = r0 + chunk; if (r1 > NN) r1 = NN;
    float s[8] = {}, q2[8] = {};
    for (int r = r0 + rg; r < r1; r += RPI) {
        uint4 v = X[(size_t)r * Q + tq];
        const __half2* hp = (const __half2*)&v;
        #pragma unroll
        for (int k = 0; k < 4; k++) {
            float2 f = __half22float2(hp[k]);
            s[2 * k] += f.x;  s[2 * k + 1] += f.y;
            q2[2 * k] += f.x * f.x; q2[2 * k + 1] += f.y * f.y;
        }
    }
    __shared__ float ls[2048], ls2[2048];
    #pragma unroll
    for (int k = 0; k < 8; k++) {
        ls[threadIdx.x * 8 + k]  = s[k];
        ls2[threadIdx.x * 8 + k] = q2[k];
    }
    __syncthreads();
    if (threadIdx.x < Q) {
        #pragma unroll 2
        for (int g = 1; g < RPI; g++)
            #pragma unroll
            for (int k = 0; k < 8; k++) {
                s[k]  += ls[(g * Q + threadIdx.x) * 8 + k];
                q2[k] += ls2[(g * Q + threadIdx.x) * 8 + k];
            }
        #pragma unroll
        for (int k = 0; k < 8; k++) {
            partial[(size_t)blockIdx.x * 2 * D + threadIdx.x * 8 + k]     = s[k];
            partial[(size_t)blockIdx.x * 2 * D + D + threadIdx.x * 8 + k] = q2[k];
        }
    }
}

// ---- R9: grid-parallel mid-reduce: 64 partial rows per block -> 1 row
template<int D>
__global__ __launch_bounds__(256) void k_bnmid(const float* __restrict__ partial,
                                               int P, float* __restrict__ outp) {
    constexpr int F   = 2 * D;
    constexpr int FPT = (F + 255) / 256;
    int b0 = blockIdx.x * 64;
    int b1 = b0 + 64; if (b1 > P) b1 = P;
    float s[FPT];
    #pragma unroll
    for (int k = 0; k < FPT; k++) s[k] = 0.f;
    for (int b = b0; b < b1; b++) {
        #pragma unroll
        for (int k = 0; k < FPT; k++) {
            int f = threadIdx.x + k * 256;
            if (f < F) s[k] += partial[(size_t)b * F + f];
        }
    }
    #pragma unroll
    for (int k = 0; k < FPT; k++) {
        int f = threadIdx.x + k * 256;
        if (f < F) outp[(size_t)blockIdx.x * F + f] = s[k];
    }
}

// final reduce over P partial rows of [D sums][D sqs]
template<int D>
__global__ __launch_bounds__(1024) void k_bnfinP(const float* __restrict__ partial,
                                                 int P,
                                                 const float* __restrict__ g,
                                                 const float* __restrict__ be,
                                                 float* __restrict__ AB) {
    constexpr int G = 1024 / D;
    int f  = threadIdx.x % D;
    int gr = threadIdx.x / D;
    float sum = 0.f, sq = 0.f;
    for (int b = gr; b < P; b += G) {
        sum += partial[(size_t)b * 2 * D + f];
        sq  += partial[(size_t)b * 2 * D + D + f];
    }
    __shared__ float ls[1024], ls2[1024];
    ls[threadIdx.x] = sum; ls2[threadIdx.x] = sq;
    __syncthreads();
    if (threadIdx.x < D) {
        float a = ls[threadIdx.x], b = ls2[threadIdx.x];
        for (int k = 1; k < G; k++) {
            a += ls[k * D + threadIdx.x];
            b += ls2[k * D + threadIdx.x];
        }
        float mu  = a / (float)NN;
        float var = b / (float)NN - mu * mu;
        var = fmaxf(var, 0.f);
        float inv = rsqrtf(var + EPSB);
        float sc = g[threadIdx.x] * inv;
        AB[threadIdx.x]     = sc;
        AB[D + threadIdx.x] = be[threadIdx.x] - mu * sc;
    }
}

// final-layer BN+ReLU fp16->fp16 (d=32)
__global__ void k_norm16h(const uint4* __restrict__ X, const float* __restrict__ AB,
                          uint4* __restrict__ Y) {
    int t = blockIdx.x * blockDim.x + threadIdx.x;
    if (t >= NN * 4) return;
    int f0 = (t & 3) * 8;
    uint4 v = X[t];
    const __half2* hp = (const __half2*)&v;
    float x[8];
    #pragma unroll
    for (int k = 0; k < 4; k++) {
        float2 f = __half22float2(hp[k]);
        x[2 * k] = f.x; x[2 * k + 1] = f.y;
    }
    uint4 ov;
    __half2* op = (__half2*)&ov;
    #pragma unroll
    for (int k = 0; k < 4; k++) {
        float o0 = fmaxf(x[2 * k] * AB[f0 + 2 * k] + AB[32 + f0 + 2 * k], 0.f);
        float o1 = fmaxf(x[2 * k + 1] * AB[f0 + 2 * k + 1] + AB[32 + f0 + 2 * k + 1], 0.f);
        op[k] = __floats2half2_rn(o0, o1);
    }
    Y[t] = ov;
}

// ---------------------------------------------------------------- final edge MLP

__global__ __launch_bounds__(256) void k_edge16(const uint4* __restrict__ X,
                                                const int* __restrict__ src,
                                                const int* __restrict__ dst,
                                                const float* __restrict__ fcw,
                                                const float* __restrict__ fcb,
                                                float* __restrict__ out) {
    int lane = threadIdx.x & 3;
    size_t t = (size_t)blockIdx.x * 256 + threadIdx.x;
    int eid = (int)(t >> 2);
    if (eid >= EE) return;
    int s = src[eid], d = dst[eid];
    uint4 av = X[(size_t)s * 4 + lane];
    uint4 bv = X[(size_t)d * 4 + lane];
    const __half2* ap = (const __half2*)&av;
    const __half2* bp2 = (const __half2*)&bv;
    float v = 0.f;
    #pragma unroll
    for (int k = 0; k < 4; k++) {
        float2 fa = __half22float2(ap[k]);
        float2 fb = __half22float2(bp2[k]);
        float w0 = fcw[lane * 8 + 2 * k];
        float w1 = fcw[lane * 8 + 2 * k + 1];
        v += fa.x * fb.x * w0 + fa.y * fb.y * w1;
    }
    v += __shfl_xor(v, 1, 4);
    v += __shfl_xor(v, 2, 4);
    if (lane == 0) out[eid] = 1.f / (1.f + expf(-(v + fcb[0])));
}

// ---------------------------------------------------------------- launch

extern "C" void kernel_launch(void* const* d_in, const int* in_sizes, int n_in,
                              void* d_out, int out_size, void* d_ws, size_t ws_size,
                              hipStream_t stream) {
    const float* x0 = (const float*)d_in[0];
    const int* ei   = (const int*)d_in[1];
    const int* srcv = ei;
    const int* dstv = ei + EE;
    const float *W[5], *bp[5], *gp[5], *bep[5];
    int idx = 2;
    for (int l = 0; l < 5; l++) {
        W[l]   = (const float*)d_in[idx++];
        bp[l]  = (const float*)d_in[idx++];
        gp[l]  = (const float*)d_in[idx++];
        bep[l] = (const float*)d_in[idx++];
    }
    const float* fcw = (const float*)d_in[22];
    const float* fcb = (const float*)d_in[23];

    char* ws = (char*)d_ws;
    size_t off = 0;
    auto alloc = [&](size_t bytes) -> void* {
        void* p = ws + off;
        off = (off + bytes + 255) & ~(size_t)255;
        return p;
    };
    __half*   conv16  = (__half*)  alloc((size_t)NN * 256 * 2);   // fp16 conv-out
    __half*   act16   = (__half*)  alloc((size_t)NN * 256 * 2);
    __half*   x16     = (__half*)  alloc((size_t)NN * 128 * 2);
    __half*   Hh      = (__half*)  alloc((size_t)NN * 128 * 2);
    unsigned* barr    = (unsigned*)alloc((size_t)NB * BCAP * 4);
    int*      colv    = (int*)     alloc((size_t)EE * 4);
    int*      rowptr  = (int*)     alloc((size_t)NN * 4);
    int*      degcnt  = (int*)     alloc((size_t)NN * 4);
    float*    dis     = (float*)   alloc((size_t)NN * 4);
    int*      bcur    = (int*)     alloc((size_t)NB * 4);
    int*      scnblk  = (int*)     alloc(4096);
    float*    part    = (float*)   alloc((size_t)6250 * 256 * 4); // 6.4MB partials
    float*    pmid    = (float*)   alloc((size_t)128 * 512 * 4);  // 256KB mid rows
    float*    bnAB    = (float*)   alloc(512 * 4);
    __half*   Wp      = (__half*)  alloc((size_t)92160 * 2);
    float*    scq     = (float*)   alloc((size_t)NN * 16 * 4);
    const int woff[5] = {0, 16384, 49152, 81920, 90112};

    // q8 rows live in barr's region (dead after CSR build): NN*128 B = 12.8MB
    unsigned char* q8 = (unsigned char*)barr;

    // ---- CSR build (binned counting sort)
    hipMemsetAsync(bcur, 0, (size_t)NB * 4, stream);
    k_bscat<<<(EE + 4095) / 4096, 256, 0, stream>>>(srcv, dstv, bcur, barr);
    k_bdeg<<<NB, 1024, 0, stream>>>(bcur, barr, degcnt, dis);
    int nScanBlk = (NN + 1023) / 1024;
    k_scan_block<<<nScanBlk, 1024, 0, stream>>>(degcnt, rowptr, scnblk, NN);
    k_scan_top<<<1, 64, 0, stream>>>(scnblk, nScanBlk);
    k_scan_add<<<nScanBlk, 1024, 0, stream>>>(rowptr, scnblk, NN);
    k_place<<<NB, 1024, 0, stream>>>(bcur, barr, rowptr, colv);

    // ---- casts / weight packs
    k_f2h<<<(NN * 128 / 4 + 255) / 256, 256, 0, stream>>>(
        (const float4*)x0, (uint2*)x16, NN * 128 / 4);
    k_wpack_all<<<(92160 + 255) / 256, 256, 0, stream>>>(W[0], W[1], W[2], W[3], W[4], Wp);

    int gx = (NN + 127) / 128;

    // two-stage BN reduce helper counts
    const int P0 = (NN + 31) / 32;   // 3125 (L0, L3)
    const int P2 = (NN + 15) / 16;   // 6250 (L2)
    const int P4 = (NN + 63) / 64;   // 1563 (L4)

    // ---- layer 0: mgemm(x16)->Hh ; q8p8 ; agg_q8s(+b0,fused BN)->conv16 ; bnmid+fin ; nscale_q8
    {
        dim3 grid(gx, 128 / 64);
        k_mgemm<4, true, false, false, false><<<grid, 256, 0, stream>>>(
            x16, Wp + woff[0], Hh, NN, 128, 128, dis, nullptr, nullptr);
        k_q8p8<<<NN * 16 / 256, 256, 0, stream>>>((const uint4*)Hh, (uint2*)q8, scq, NN * 16);
        k_agg_q8s<<<P0, 256, 0, stream>>>(
            (const uint4*)q8, scq, conv16, rowptr, degcnt, colv, dis, bp[0], part);
        int m0 = (P0 + 63) / 64;
        k_bnmid<128><<<m0, 256, 0, stream>>>(part, P0, pmid);
        k_bnfinP<128><<<1, 1024, 0, stream>>>(pmid, m0, gp[0], bep[0], bnAB);
        k_nscale_q8<<<(NN * 16 + 255) / 256, 256, 0, stream>>>(conv16, bnAB, dis, (uint2*)q8, scq);
    }
    // ---- layer 1 (agg first): agg_q8u->act16 ; mgemm(+b1, fp16 out)->conv16 ; bnpart_h ; bnmid+fin
    {
        k_agg_q8u<<<P0, 256, 0, stream>>>(
            (const uint4*)q8, scq, act16, rowptr, degcnt, colv, dis);
        dim3 grid(gx, 256 / 64);
        k_mgemm<4, false, false, false, true><<<grid, 256, 0, stream>>>(
            act16, Wp + woff[1], conv16, NN, 128, 256, nullptr, bp[1], nullptr);
        k_bnpart_h<256><<<BNBLK, 256, 0, stream>>>((const uint4*)conv16, part);
        int m1 = (BNBLK + 63) / 64;
        k_bnmid<256><<<m1, 256, 0, stream>>>(part, BNBLK, pmid);
        k_bnfinP<256><<<1, 1024, 0, stream>>>(pmid, m1, gp[1], bep[1], bnAB);
    }
    // ---- layer 2: mgemm(ABN16 d=256)->Hh ; agg_hf<16>(+b2,fused)->conv16 ; bnmid+fin
    {
        dim3 grid(gx, 128 / 64);
        k_mgemm<4, true, true, true, false><<<grid, 256, 0, stream>>>(
            conv16, Wp + woff[2], Hh, NN, 256, 128, dis, nullptr, bnAB);
        k_agg_hf<16><<<P2, 256, 0, stream>>>(
            (const uint4*)Hh, conv16, rowptr, degcnt, colv, dis, bp[2], part);
        int m2 = (P2 + 63) / 64;
        k_bnmid<128><<<m2, 256, 0, stream>>>(part, P2, pmid);
        k_bnfinP<128><<<1, 1024, 0, stream>>>(pmid, m2, gp[2], bep[2], bnAB);
    }
    // ---- layer 3 (d=64): mgemm(ABN16 d=128)->Hh ; agg_hf<8>(+b3,fused)->conv16 ; bnmid+fin
    {
        dim3 grid(gx, 64 / 64);
        k_mgemm<4, true, true, true, false><<<grid, 256, 0, stream>>>(
            conv16, Wp + woff[3], Hh, NN, 128, 64, dis, nullptr, bnAB);
        k_agg_hf<8><<<P0, 256, 0, stream>>>(
            (const uint4*)Hh, conv16, rowptr, degcnt, colv, dis, bp[3], part);
        int m3 = (P0 + 63) / 64;
        k_bnmid<64><<<m3, 256, 0, stream>>>(part, P0, pmid);
        k_bnfinP<64><<<1, 1024, 0, stream>>>(pmid, m3, gp[3], bep[3], bnAB);
    }
    // ---- layer 4 (d=32): mgemm(ABN16 d=64)->Hh ; agg_hf<4>(+b4,fused)->conv16 ; bnmid+fin ; norm16h
    {
        dim3 grid(gx, 1);
        k_mgemm<2, true, true, true, false><<<grid, 256, 0, stream>>>(
            conv16, Wp + woff[4], Hh, NN, 64, 32, dis, nullptr, bnAB);
        k_agg_hf<4><<<P4, 256, 0, stream>>>(
            (const uint4*)Hh, conv16, rowptr, degcnt, colv, dis, bp[4], part);
        int m4 = (P4 + 63) / 64;
        k_bnmid<32><<<m4, 256, 0, stream>>>(part, P4, pmid);
        k_bnfinP<32><<<1, 1024, 0, stream>>>(pmid, m4, gp[4], bep[4], bnAB);
        k_norm16h<<<(NN * 4 + 255) / 256, 256, 0, stream>>>(
            (const uint4*)conv16, bnAB, (uint4*)act16);
    }

    size_t edgeThreads = (size_t)EE * 4;
    k_edge16<<<(unsigned)((edgeThreads + 255) / 256), 256, 0, stream>>>(
        (const uint4*)act16, srcv, dstv, fcw, fcb, (float*)d_out);
}

// Round 10
// 936.801 us; speedup vs baseline: 2.0631x; 1.0258x over previous
//
#include <hip/hip_runtime.h>
#include <hip/hip_fp16.h>
#include <cstddef>

#define NN 100000
#define EE 3200000
#define EPSB 1e-5f
#define NB 391      // buckets = ceil(NN/256)
#define BCAP 10240  // per-bucket edge capacity
#define BNBLK 512   // BN partial blocks for the L1 GEMM path

typedef _Float16 half8 __attribute__((ext_vector_type(8)));
typedef float floatx4 __attribute__((ext_vector_type(4)));

// ---------------------------------------------------------------- CSR build
// packed record: src (17 bits) | dst&255 (8 bits) << 17

__global__ __launch_bounds__(256) void k_bscat(const int* __restrict__ src,
                                               const int* __restrict__ dst,
                                               int* __restrict__ bcur,
                                               unsigned* __restrict__ barr) {
    __shared__ int hist[NB];
    __shared__ int base[NB];
    int tid = threadIdx.x;
    for (int b = tid; b < NB; b += 256) hist[b] = 0;
    __syncthreads();
    int e0 = blockIdx.x * 4096;
    int d[16], s[16];
    #pragma unroll
    for (int j = 0; j < 16; j++) {
        int e = e0 + j * 256 + tid;
        if (e < EE) {
            d[j] = dst[e];
            s[j] = src[e];
            atomicAdd(&hist[d[j] >> 8], 1);
        } else d[j] = -1;
    }
    __syncthreads();
    for (int b = tid; b < NB; b += 256) {
        int c = hist[b];
        base[b] = (c > 0) ? atomicAdd(&bcur[b], c) : 0;
        hist[b] = 0;
    }
    __syncthreads();
    #pragma unroll
    for (int j = 0; j < 16; j++) {
        if (d[j] >= 0) {
            int b = d[j] >> 8;
            int r = atomicAdd(&hist[b], 1);
            barr[(size_t)b * BCAP + base[b] + r] =
                (unsigned)s[j] | ((unsigned)(d[j] & 255) << 17);
        }
    }
}

__global__ __launch_bounds__(1024) void k_bdeg(const int* __restrict__ bcur,
                                               const unsigned* __restrict__ barr,
                                               int* __restrict__ degcnt,
                                               float* __restrict__ dis) {
    __shared__ int h[256];
    int b = blockIdx.x;
    if (threadIdx.x < 256) h[threadIdx.x] = 0;
    __syncthreads();
    int cnt = bcur[b];
    const unsigned* p = barr + (size_t)b * BCAP;
    for (int t = threadIdx.x; t < cnt; t += 1024)
        atomicAdd(&h[(p[t] >> 17) & 255], 1);
    __syncthreads();
    if (threadIdx.x < 256) {
        int node = (b << 8) + threadIdx.x;
        if (node < NN) {
            int dg = h[threadIdx.x];
            degcnt[node] = dg;
            dis[node] = rsqrtf((float)dg + 1.0f);
        }
    }
}

__global__ __launch_bounds__(1024) void k_place(const int* __restrict__ bcur,
                                                const unsigned* __restrict__ barr,
                                                const int* __restrict__ rowptr,
                                                int* __restrict__ col) {
    __shared__ int cur[256];
    int b = blockIdx.x;
    if (threadIdx.x < 256) {
        int node = (b << 8) + threadIdx.x;
        cur[threadIdx.x] = (node < NN) ? rowptr[node] : 0;
    }
    __syncthreads();
    int cnt = bcur[b];
    const unsigned* p = barr + (size_t)b * BCAP;
    for (int t = threadIdx.x; t < cnt; t += 1024) {
        unsigned e = p[t];
        int pos = atomicAdd(&cur[(e >> 17) & 255], 1);
        col[pos] = (int)(e & 0x1FFFFu);
    }
}

__global__ void k_scan_block(const int* __restrict__ in, int* __restrict__ out,
                             int* __restrict__ blksum, int n) {
    __shared__ int s[1024];
    int i = blockIdx.x * 1024 + threadIdx.x;
    int v = (i < n) ? in[i] : 0;
    s[threadIdx.x] = v;
    __syncthreads();
    for (int off = 1; off < 1024; off <<= 1) {
        int t = (threadIdx.x >= off) ? s[threadIdx.x - off] : 0;
        __syncthreads();
        s[threadIdx.x] += t;
        __syncthreads();
    }
    if (i < n) out[i] = s[threadIdx.x] - v;  // exclusive
    if (threadIdx.x == 1023) blksum[blockIdx.x] = s[1023];
}

__global__ void k_scan_top(int* __restrict__ blksum, int nb) {
    if (threadIdx.x == 0) {
        int acc = 0;
        for (int b = 0; b < nb; b++) { int v = blksum[b]; blksum[b] = acc; acc += v; }
    }
}

__global__ void k_scan_add(int* __restrict__ out, const int* __restrict__ blksum, int n) {
    int i = blockIdx.x * 1024 + threadIdx.x;
    if (i < n) out[i] += blksum[blockIdx.x];
}

// ---------------------------------------------------------------- packing

__global__ void k_wpack_all(const float* __restrict__ W0, const float* __restrict__ W1,
                            const float* __restrict__ W2, const float* __restrict__ W3,
                            const float* __restrict__ W4, __half* __restrict__ Wp) {
    const int offs[6] = {0, 16384, 49152, 81920, 90112, 92160};
    const int Ks[5] = {128, 128, 256, 128, 64};
    const int Ns[5] = {128, 256, 128, 64, 32};
    const float* Ws[5] = {W0, W1, W2, W3, W4};
    int t = blockIdx.x * blockDim.x + threadIdx.x;
    if (t >= 92160) return;
    int l = 0;
    while (t >= offs[l + 1]) l++;
    int local = t - offs[l];
    int N = Ns[l], K = Ks[l];
    int k = local / N, n = local - k * N;
    Wp[(size_t)offs[l] + (size_t)n * K + k] = __float2half(Ws[l][local]);
}

// ---------------------------------------------------------------- MFMA GEMM
// modes: OUT16: C fp16 = dis*acc (agg operand, Hh). CH16: C fp16 = acc+bias
// (conv-out). ABN: BN+ReLU during A staging; AH16: ABN input fp16.
// AF32: non-ABN A staging reads fp32 and converts (removes f2h pass).

template<int NT, bool OUT16, bool ABN, bool AH16, bool CH16, bool AF32>
__global__ __launch_bounds__(256) void k_mgemm(const void* __restrict__ Av,
                                               const __half* __restrict__ Wp,
                                               void* __restrict__ Cv,
                                               int M, int K, int N,
                                               const float* __restrict__ dis,
                                               const float* __restrict__ bias,
                                               const float* __restrict__ AB) {
    constexpr int TN = NT * 16;
    __shared__ __half Ash[128][40];
    __shared__ __half Bsh[TN][40];
    int tid  = threadIdx.x;
    int wave = tid >> 6;
    int lane = tid & 63;
    int quad = lane >> 4;
    int l16  = lane & 15;
    int bm = blockIdx.x * 128;
    int bn = blockIdx.y * TN;

    floatx4 acc[2][NT];
    #pragma unroll
    for (int mt = 0; mt < 2; mt++)
        #pragma unroll
        for (int nt = 0; nt < NT; nt++)
            acc[mt][nt] = (floatx4){0.f, 0.f, 0.f, 0.f};

    for (int k0 = 0; k0 < K; k0 += 32) {
        #pragma unroll
        for (int it = 0; it < 2; it++) {
            int u = tid + it * 256;
            int row = u >> 2, seg = u & 3;
            int grow = bm + row;
            if (ABN) {
                int f0 = k0 + seg * 8;
                uint4 o = make_uint4(0, 0, 0, 0);
                if (grow < M) {
                    float x[8];
                    if (AH16) {
                        const __half* Af = (const __half*)Av;
                        uint4 xv = *(const uint4*)&Af[(size_t)grow * K + f0];
                        const __half2* xp = (const __half2*)&xv;
                        #pragma unroll
                        for (int k = 0; k < 4; k++) {
                            float2 f = __half22float2(xp[k]);
                            x[2 * k] = f.x; x[2 * k + 1] = f.y;
                        }
                    } else {
                        const float* Af = (const float*)Av;
                        float4 x0 = *(const float4*)&Af[(size_t)grow * K + f0];
                        float4 x1 = *(const float4*)&Af[(size_t)grow * K + f0 + 4];
                        x[0] = x0.x; x[1] = x0.y; x[2] = x0.z; x[3] = x0.w;
                        x[4] = x1.x; x[5] = x1.y; x[6] = x1.z; x[7] = x1.w;
                    }
                    float4 a0 = *(const float4*)&AB[f0];
                    float4 a1 = *(const float4*)&AB[f0 + 4];
                    float4 c0 = *(const float4*)&AB[K + f0];
                    float4 c1 = *(const float4*)&AB[K + f0 + 4];
                    float h0 = fmaxf(x[0] * a0.x + c0.x, 0.f);
                    float h1 = fmaxf(x[1] * a0.y + c0.y, 0.f);
                    float h2 = fmaxf(x[2] * a0.z + c0.z, 0.f);
                    float h3 = fmaxf(x[3] * a0.w + c0.w, 0.f);
                    float h4 = fmaxf(x[4] * a1.x + c1.x, 0.f);
                    float h5 = fmaxf(x[5] * a1.y + c1.y, 0.f);
                    float h6 = fmaxf(x[6] * a1.z + c1.z, 0.f);
                    float h7 = fmaxf(x[7] * a1.w + c1.w, 0.f);
                    union { __half2 h; unsigned u; } p0, p1, p2, p3;
                    p0.h = __floats2half2_rn(h0, h1);
                    p1.h = __floats2half2_rn(h2, h3);
                    p2.h = __floats2half2_rn(h4, h5);
                    p3.h = __floats2half2_rn(h6, h7);
                    o = make_uint4(p0.u, p1.u, p2.u, p3.u);
                }
                *(uint4*)&Ash[row][seg * 8] = o;
            } else {
                uint4 v = make_uint4(0, 0, 0, 0);
                if (AF32) {
                    const float* Af = (const float*)Av;
                    if (grow < M) {
                        float4 x0 = *(const float4*)&Af[(size_t)grow * K + k0 + seg * 8];
                        float4 x1 = *(const float4*)&Af[(size_t)grow * K + k0 + seg * 8 + 4];
                        union { __half2 h; unsigned u; } p0, p1, p2, p3;
                        p0.h = __floats2half2_rn(x0.x, x0.y);
                        p1.h = __floats2half2_rn(x0.z, x0.w);
                        p2.h = __floats2half2_rn(x1.x, x1.y);
                        p3.h = __floats2half2_rn(x1.z, x1.w);
                        v = make_uint4(p0.u, p1.u, p2.u, p3.u);
                    }
                } else {
                    const __half* A = (const __half*)Av;
                    if (grow < M) v = *(const uint4*)&A[(size_t)grow * K + k0 + seg * 8];
                }
                *(uint4*)&Ash[row][seg * 8] = v;
            }
        }
        if (tid < TN * 4) {
            int n = tid >> 2, seg = tid & 3;
            uint4 v = *(const uint4*)&Wp[(size_t)(bn + n) * K + k0 + seg * 8];
            *(uint4*)&Bsh[n][seg * 8] = v;
        }
        __syncthreads();
        half8 a[2], b[NT];
        #pragma unroll
        for (int mt = 0; mt < 2; mt++)
            a[mt] = *(const half8*)&Ash[wave * 32 + mt * 16 + l16][quad * 8];
        #pragma unroll
        for (int nt = 0; nt < NT; nt++)
            b[nt] = *(const half8*)&Bsh[nt * 16 + l16][quad * 8];
        #pragma unroll
        for (int mt = 0; mt < 2; mt++)
            #pragma unroll
            for (int nt = 0; nt < NT; nt++)
                acc[mt][nt] = __builtin_amdgcn_mfma_f32_16x16x32_f16(
                    a[mt], b[nt], acc[mt][nt], 0, 0, 0);
        __syncthreads();
    }

    #pragma unroll
    for (int mt = 0; mt < 2; mt++) {
        #pragma unroll
        for (int r = 0; r < 4; r++) {
            int grow = bm + wave * 32 + mt * 16 + quad * 4 + r;
            if (grow >= M) continue;
            if (OUT16) {
                float ds = dis[grow];
                __half* C = (__half*)Cv;
                #pragma unroll
                for (int nt = 0; nt < NT; nt++) {
                    int gcol = bn + nt * 16 + l16;
                    C[(size_t)grow * N + gcol] = __float2half(ds * acc[mt][nt][r]);
                }
            } else if (CH16) {
                __half* C = (__half*)Cv;
                #pragma unroll
                for (int nt = 0; nt < NT; nt++) {
                    int gcol = bn + nt * 16 + l16;
                    C[(size_t)grow * N + gcol] = __float2half(acc[mt][nt][r] + bias[gcol]);
                }
            } else {
                float* C = (float*)Cv;
                #pragma unroll
                for (int nt = 0; nt < NT; nt++) {
                    int gcol = bn + nt * 16 + l16;
                    C[(size_t)grow * N + gcol] = acc[mt][nt][r] + bias[gcol];
                }
            }
        }
    }
}

// ---------------------------------------------------------------- int8 quant
// L0 operand: signed, per-8-feature scales; L1 operand: unsigned per-16.

__global__ __launch_bounds__(256) void k_q8p8(const uint4* __restrict__ H,
                                              uint2* __restrict__ q8,
                                              float* __restrict__ scq, int total) {
    int t = blockIdx.x * 256 + threadIdx.x;
    if (t >= total) return;
    uint4 v = H[t];
    const __half2* hp = (const __half2*)&v;
    float h[8];
    #pragma unroll
    for (int k = 0; k < 4; k++) {
        float2 f = __half22float2(hp[k]);
        h[2 * k] = f.x; h[2 * k + 1] = f.y;
    }
    float m = fabsf(h[0]);
    #pragma unroll
    for (int k = 1; k < 8; k++) m = fmaxf(m, fabsf(h[k]));
    float inv = m > 0.f ? 127.f / m : 0.f;
    unsigned b[8];
    #pragma unroll
    for (int k = 0; k < 8; k++) {
        float f = fminf(fmaxf(h[k] * inv, -127.f), 127.f);
        b[k] = (unsigned)(f + 128.5f);
    }
    q8[t] = make_uint2(b[0] | (b[1] << 8) | (b[2] << 16) | (b[3] << 24),
                       b[4] | (b[5] << 8) | (b[6] << 16) | (b[7] << 24));
    scq[t] = m * (1.f / 127.f);
}

// L1 fused BN+ReLU+dis-scale -> unsigned q8 (d=128, 16 threads/row), fp16 input
__global__ void k_nscale_q8(const __half* __restrict__ X, const float* __restrict__ AB,
                            const float* __restrict__ dis, uint2* __restrict__ q8,
                            float* __restrict__ scq) {
    int t = blockIdx.x * blockDim.x + threadIdx.x;
    if (t >= NN * 16) return;
    int row = t >> 4;
    int sub = t & 15;
    int f0 = sub * 8;
    float ds = dis[row];
    uint4 xv = ((const uint4*)X)[(size_t)row * 16 + sub];
    const __half2* xp = (const __half2*)&xv;
    float x[8];
    #pragma unroll
    for (int k = 0; k < 4; k++) {
        float2 f = __half22float2(xp[k]);
        x[2 * k] = f.x; x[2 * k + 1] = f.y;
    }
    float4 a0 = *(const float4*)&AB[f0];
    float4 a1 = *(const float4*)&AB[f0 + 4];
    float4 c0 = *(const float4*)&AB[128 + f0];
    float4 c1 = *(const float4*)&AB[128 + f0 + 4];
    float h[8];
    h[0] = ds * fmaxf(x[0] * a0.x + c0.x, 0.f);
    h[1] = ds * fmaxf(x[1] * a0.y + c0.y, 0.f);
    h[2] = ds * fmaxf(x[2] * a0.z + c0.z, 0.f);
    h[3] = ds * fmaxf(x[3] * a0.w + c0.w, 0.f);
    h[4] = ds * fmaxf(x[4] * a1.x + c1.x, 0.f);
    h[5] = ds * fmaxf(x[5] * a1.y + c1.y, 0.f);
    h[6] = ds * fmaxf(x[6] * a1.z + c1.z, 0.f);
    h[7] = ds * fmaxf(x[7] * a1.w + c1.w, 0.f);
    float m = h[0];
    #pragma unroll
    for (int k = 1; k < 8; k++) m = fmaxf(m, h[k]);
    m = fmaxf(m, __shfl_xor(m, 1));   // 16-feat group max
    float inv = m > 0.f ? 255.f / m : 0.f;
    unsigned b[8];
    #pragma unroll
    for (int k = 0; k < 8; k++)
        b[k] = (unsigned)(fminf(h[k] * inv, 255.f) + 0.5f);
    q8[t] = make_uint2(b[0] | (b[1] << 8) | (b[2] << 16) | (b[3] << 24),
                       b[4] | (b[5] << 8) | (b[6] << 16) | (b[7] << 24));
    if ((t & 1) == 0) scq[t >> 1] = m * (1.f / 255.f);
}

// ---------------------------------------------------------------- aggregation
// Lessons pinned:
//  - R4: byte-shrinking a latency-bound random gather is worthless.
//  - R5/R7: locality engineering fails; ~113us/d=128 gather floor stands
//    (~3.6 TB/s random L2-miss path ceiling).
//  - R8/R9: BN partials fused in agg epilogue; two-stage final reduce.

__device__ __forceinline__ void acc_q8s2(float* acc, const uint4& r,
                                         const float2& s, float& c0, float& c1) {
    const unsigned* w = (const unsigned*)&r;
    c0 += s.x; c1 += s.y;
    #pragma unroll
    for (int q = 0; q < 4; q++) {
        unsigned v = w[q];
        float sq = (q < 2) ? s.x : s.y;
        acc[4 * q + 0] = fmaf(sq, (float)(v & 0xffu), acc[4 * q + 0]);
        acc[4 * q + 1] = fmaf(sq, (float)((v >> 8) & 0xffu), acc[4 * q + 1]);
        acc[4 * q + 2] = fmaf(sq, (float)((v >> 16) & 0xffu), acc[4 * q + 2]);
        acc[4 * q + 3] = fmaf(sq, (float)(v >> 24), acc[4 * q + 3]);
    }
}

// L0: signed q8 gather -> fp16 conv-out + fused BN partials (d=128, 8 lanes/node)
__global__ __launch_bounds__(256) void k_agg_q8s(const uint4* __restrict__ Q,
                                                 const float* __restrict__ sc,
                                                 __half* __restrict__ outh,
                                                 const int* __restrict__ rowptr,
                                                 const int* __restrict__ degcnt,
                                                 const int* __restrict__ colv,
                                                 const float* __restrict__ dis,
                                                 const float* __restrict__ bias,
                                                 float* __restrict__ part) {
    int g    = threadIdx.x >> 3;
    int lane = threadIdx.x & 7;
    int i = blockIdx.x * 32 + g;
    bool alive = i < NN;
    int beg = alive ? rowptr[i] : 0;
    int cnt = alive ? degcnt[i] : 0;
    const uint4*  base = Q + lane;
    const float2* scb  = (const float2*)sc + lane;
    float acc[16] = {};
    float c0 = 0.f, c1 = 0.f;
    int e = 0;
    for (; e + 8 <= cnt; e += 8) {
        int c[8];
        #pragma unroll
        for (int j = 0; j < 8; j++) c[j] = colv[beg + e + j];
        uint4 r[8];
        float2 s[8];
        #pragma unroll
        for (int j = 0; j < 8; j++) {
            r[j] = base[(size_t)c[j] * 8];
            s[j] = scb[(size_t)c[j] * 8];
        }
        #pragma unroll
        for (int j = 0; j < 8; j++) acc_q8s2(acc, r[j], s[j], c0, c1);
    }
    for (; e < cnt; e++) {
        int c = colv[beg + e];
        acc_q8s2(acc, base[(size_t)c * 8], scb[(size_t)c * 8], c0, c1);
    }
    if (alive) acc_q8s2(acc, base[(size_t)i * 8], scb[(size_t)i * 8], c0, c1);
    float ds = alive ? dis[i] : 0.f;
    float zp0 = 128.f * c0, zp1 = 128.f * c1;
    const float4* bi = (const float4*)bias;
    float o[16];
    #pragma unroll
    for (int j = 0; j < 4; j++) {
        float4 b = bi[lane * 4 + j];
        o[4 * j + 0] = alive ? ds * (acc[4 * j + 0] - (j < 2 ? zp0 : zp1)) + b.x : 0.f;
        o[4 * j + 1] = alive ? ds * (acc[4 * j + 1] - (j < 2 ? zp0 : zp1)) + b.y : 0.f;
        o[4 * j + 2] = alive ? ds * (acc[4 * j + 2] - (j < 2 ? zp0 : zp1)) + b.z : 0.f;
        o[4 * j + 3] = alive ? ds * (acc[4 * j + 3] - (j < 2 ? zp0 : zp1)) + b.w : 0.f;
    }
    if (alive) {
        uint4 ov0, ov1;
        __half2* p0 = (__half2*)&ov0;
        __half2* p1 = (__half2*)&ov1;
        #pragma unroll
        for (int k = 0; k < 4; k++) {
            p0[k] = __floats2half2_rn(o[2 * k], o[2 * k + 1]);
            p1[k] = __floats2half2_rn(o[8 + 2 * k], o[9 + 2 * k]);
        }
        uint4* out = (uint4*)outh;
        out[(size_t)i * 16 + lane * 2]     = ov0;
        out[(size_t)i * 16 + lane * 2 + 1] = ov1;
    }
    // fused BN partials (from fp32 o[], pre-rounding)
    __shared__ float lsh[32][129];
    #pragma unroll
    for (int k = 0; k < 16; k++) lsh[g][lane * 16 + k] = o[k];
    __syncthreads();
    if (threadIdx.x < 128) {
        float s = 0.f, q = 0.f;
        #pragma unroll 4
        for (int gg = 0; gg < 32; gg++) {
            float v = lsh[gg][threadIdx.x];
            s += v; q += v * v;
        }
        part[(size_t)blockIdx.x * 256 + threadIdx.x]       = s;
        part[(size_t)blockIdx.x * 256 + 128 + threadIdx.x] = q;
    }
}

// L1: unsigned q8 gather -> fp16 GEMM operand
__device__ __forceinline__ void acc_q8u(float* acc, const uint4& r, float s) {
    const unsigned* w = (const unsigned*)&r;
    #pragma unroll
    for (int q = 0; q < 4; q++) {
        unsigned v = w[q];
        acc[4 * q + 0] = fmaf(s, (float)(v & 0xffu), acc[4 * q + 0]);
        acc[4 * q + 1] = fmaf(s, (float)((v >> 8) & 0xffu), acc[4 * q + 1]);
        acc[4 * q + 2] = fmaf(s, (float)((v >> 16) & 0xffu), acc[4 * q + 2]);
        acc[4 * q + 3] = fmaf(s, (float)(v >> 24), acc[4 * q + 3]);
    }
}

__global__ __launch_bounds__(256) void k_agg_q8u(const uint4* __restrict__ Q,
                                                 const float* __restrict__ sc,
                                                 __half* __restrict__ out16,
                                                 const int* __restrict__ rowptr,
                                                 const int* __restrict__ degcnt,
                                                 const int* __restrict__ colv,
                                                 const float* __restrict__ dis) {
    int g    = threadIdx.x >> 3;
    int lane = threadIdx.x & 7;
    int i = blockIdx.x * 32 + g;
    if (i >= NN) return;
    int beg = rowptr[i];
    int cnt = degcnt[i];
    const uint4* base = Q + lane;
    const float* scb  = sc + lane;
    float acc[16] = {};
    int e = 0;
    for (; e + 8 <= cnt; e += 8) {
        int c[8];
        #pragma unroll
        for (int j = 0; j < 8; j++) c[j] = colv[beg + e + j];
        uint4 r[8];
        float s[8];
        #pragma unroll
        for (int j = 0; j < 8; j++) {
            r[j] = base[(size_t)c[j] * 8];
            s[j] = scb[(size_t)c[j] * 8];
        }
        #pragma unroll
        for (int j = 0; j < 8; j++) acc_q8u(acc, r[j], s[j]);
    }
    for (; e < cnt; e++) {
        int c = colv[beg + e];
        acc_q8u(acc, base[(size_t)c * 8], scb[(size_t)c * 8]);
    }
    acc_q8u(acc, base[(size_t)i * 8], scb[(size_t)i * 8]);
    float ds = dis[i];
    float o[16];
    #pragma unroll
    for (int k = 0; k < 16; k++) o[k] = ds * acc[k];
    uint4 ov0, ov1;
    __half2* p0 = (__half2*)&ov0;
    __half2* p1 = (__half2*)&ov1;
    #pragma unroll
    for (int k = 0; k < 4; k++) {
        p0[k] = __floats2half2_rn(o[2 * k], o[2 * k + 1]);
        p1[k] = __floats2half2_rn(o[8 + 2 * k], o[9 + 2 * k]);
    }
    uint4* out = (uint4*)out16;
    out[(size_t)i * 16 + lane * 2]     = ov0;
    out[(size_t)i * 16 + lane * 2 + 1] = ov1;
}

// fp16 row gather -> fp16 conv-out + fused BN partials. TPN=d/8 lanes/node.
// 16-deep primary pipeline (R3-verified faster than 8-deep).
__device__ __forceinline__ void acc_row(float* acc, const uint4& r) {
    const __half2* hp = (const __half2*)&r;
    #pragma unroll
    for (int k = 0; k < 4; k++) {
        float2 f2 = __half22float2(hp[k]);
        acc[2 * k]     += f2.x;
        acc[2 * k + 1] += f2.y;
    }
}

template<int TPN>
__global__ __launch_bounds__(256) void k_agg_hf(const uint4* __restrict__ Hs,
                                                __half* __restrict__ outh,
                                                const int* __restrict__ rowptr,
                                                const int* __restrict__ degcnt,
                                                const int* __restrict__ colv,
                                                const float* __restrict__ dis,
                                                const float* __restrict__ bias,
                                                float* __restrict__ part) {
    constexpr int G = 256 / TPN;
    constexpr int D = TPN * 8;
    int g    = threadIdx.x / TPN;
    int lane = threadIdx.x % TPN;
    int i = blockIdx.x * G + g;
    bool alive = i < NN;
    int beg = alive ? rowptr[i] : 0;
    int cnt = alive ? degcnt[i] : 0;
    const uint4* base = Hs + lane;
    float acc[8] = {};
    int e = 0;
    for (; e + 16 <= cnt; e += 16) {
        int c[16];
        #pragma unroll
        for (int j = 0; j < 16; j++) c[j] = colv[beg + e + j];
        uint4 r[16];
        #pragma unroll
        for (int j = 0; j < 16; j++) r[j] = base[(size_t)c[j] * TPN];
        #pragma unroll
        for (int j = 0; j < 16; j++) acc_row(acc, r[j]);
    }
    for (; e + 4 <= cnt; e += 4) {
        int c[4];
        #pragma unroll
        for (int j = 0; j < 4; j++) c[j] = colv[beg + e + j];
        uint4 r[4];
        #pragma unroll
        for (int j = 0; j < 4; j++) r[j] = base[(size_t)c[j] * TPN];
        #pragma unroll
        for (int j = 0; j < 4; j++) acc_row(acc, r[j]);
    }
    for (; e < cnt; e++) {
        uint4 r = base[(size_t)colv[beg + e] * TPN];
        acc_row(acc, r);
    }
    if (alive) {
        uint4 rs = base[(size_t)i * TPN];  // self-loop
        acc_row(acc, rs);
    }
    float ds = alive ? dis[i] : 0.f;
    float4 b0 = ((const float4*)bias)[lane * 2];
    float4 b1 = ((const float4*)bias)[lane * 2 + 1];
    float o[8];
    o[0] = alive ? ds * acc[0] + b0.x : 0.f;
    o[1] = alive ? ds * acc[1] + b0.y : 0.f;
    o[2] = alive ? ds * acc[2] + b0.z : 0.f;
    o[3] = alive ? ds * acc[3] + b0.w : 0.f;
    o[4] = alive ? ds * acc[4] + b1.x : 0.f;
    o[5] = alive ? ds * acc[5] + b1.y : 0.f;
    o[6] = alive ? ds * acc[6] + b1.z : 0.f;
    o[7] = alive ? ds * acc[7] + b1.w : 0.f;
    if (alive) {
        uint4 ov;
        __half2* op = (__half2*)&ov;
        #pragma unroll
        for (int k = 0; k < 4; k++) op[k] = __floats2half2_rn(o[2 * k], o[2 * k + 1]);
        ((uint4*)outh)[(size_t)i * TPN + lane] = ov;
    }
    // fused BN partials
    __shared__ float lsh[G][D + 1];
    #pragma unroll
    for (int k = 0; k < 8; k++) lsh[g][lane * 8 + k] = o[k];
    __syncthreads();
    if (threadIdx.x < D) {
        float s = 0.f, q = 0.f;
        #pragma unroll 4
        for (int gg = 0; gg < G; gg++) {
            float v = lsh[gg][threadIdx.x];
            s += v; q += v * v;
        }
        part[(size_t)blockIdx.x * (2 * D) + threadIdx.x]     = s;
        part[(size_t)blockIdx.x * (2 * D) + D + threadIdx.x] = q;
    }
}

// ---------------------------------------------------------------- BatchNorm
// L1 GEMM path: separate partial pass reading fp16 conv-out.

template<int D>
__global__ __launch_bounds__(256) void k_bnpart_h(const uint4* __restrict__ X,
                                                  float* __restrict__ partial) {
    constexpr int Q   = D / 8;     // uint4 (8 halfs) per row
    constexpr int RPI = 256 / Q;
    int tq = threadIdx.x % Q;
    int rg = threadIdx.x / Q;
    int chunk = (NN + BNBLK - 1) / BNBLK;
    int r0 = blockIdx.x * chunk;
    int r1 = r0 + chunk; if (r1 > NN) r1 = NN;
    float s[8] = {}, q2[8] = {};
    for (int r = r0 + rg; r < r1; r += RPI) {
        uint4 v = X[(size_t)r * Q + tq];
        const __half2* hp = (const __half2*)&v;
        #pragma unroll
        for (int k = 0; k < 4; k++) {
            float2 f = __half22float2(hp[k]);
            s[2 * k] += f.x;  s[2 * k + 1] += f.y;
            q2[2 * k] += f.x * f.x; q2[2 * k + 1] += f.y * f.y;
        }
    }
    __shared__ float ls[2048], ls2[2048];
    #pragma unroll
    for (int k = 0; k < 8; k++) {
        ls[threadIdx.x * 8 + k]  = s[k];
        ls2[threadIdx.x * 8 + k] = q2[k];
    }
    __syncthreads();
    if (threadIdx.x < Q) {
        #pragma unroll 2
        for (int g = 1; g < RPI; g++)
            #pragma unroll
            for (int k = 0; k < 8; k++) {
                s[k]  += ls[(g * Q + threadIdx.x) * 8 + k];
                q2[k] += ls2[(g * Q + threadIdx.x) * 8 + k];
            }
        #pragma unroll
        for (int k = 0; k < 8; k++) {
            partial[(size_t)blockIdx.x * 2 * D + threadIdx.x * 8 + k]     = s[k];
            partial[(size_t)blockIdx.x * 2 * D + D + threadIdx.x * 8 + k] = q2[k];
        }
    }
}

// grid-parallel mid-reduce: 64 partial rows per block -> 1 row (R9 fix)
template<int D>
__global__ __launch_bounds__(256) void k_bnmid(const float* __restrict__ partial,
                                               int P, float* __restrict__ outp) {
    constexpr int F   = 2 * D;
    constexpr int FPT = (F + 255) / 256;
    int b0 = blockIdx.x * 64;
    int b1 = b0 + 64; if (b1 > P) b1 = P;
    float s[FPT];
    #pragma unroll
    for (int k = 0; k < FPT; k++) s[k] = 0.f;
    for (int b = b0; b < b1; b++) {
        #pragma unroll
        for (int k = 0; k < FPT; k++) {
            int f = threadIdx.x + k * 256;
            if (f < F) s[k] += partial[(size_t)b * F + f];
        }
    }
    #pragma unroll
    for (int k = 0; k < FPT; k++) {
        int f = threadIdx.x + k * 256;
        if (f < F) outp[(size_t)blockIdx.x * F + f] = s[k];
    }
}

// final reduce over P partial rows of [D sums][D sqs]
template<int D>
__global__ __launch_bounds__(1024) void k_bnfinP(const float* __restrict__ partial,
                                                 int P,
                                                 const float* __restrict__ g,
                                                 const float* __restrict__ be,
                                                 float* __restrict__ AB) {
    constexpr int G = 1024 / D;
    int f  = threadIdx.x % D;
    int gr = threadIdx.x / D;
    float sum = 0.f, sq = 0.f;
    for (int b = gr; b < P; b += G) {
        sum += partial[(size_t)b * 2 * D + f];
        sq  += partial[(size_t)b * 2 * D + D + f];
    }
    __shared__ float ls[1024], ls2[1024];
    ls[threadIdx.x] = sum; ls2[threadIdx.x] = sq;
    __syncthreads();
    if (threadIdx.x < D) {
        float a = ls[threadIdx.x], b = ls2[threadIdx.x];
        for (int k = 1; k < G; k++) {
            a += ls[k * D + threadIdx.x];
            b += ls2[k * D + threadIdx.x];
        }
        float mu  = a / (float)NN;
        float var = b / (float)NN - mu * mu;
        var = fmaxf(var, 0.f);
        float inv = rsqrtf(var + EPSB);
        float sc = g[threadIdx.x] * inv;
        AB[threadIdx.x]     = sc;
        AB[D + threadIdx.x] = be[threadIdx.x] - mu * sc;
    }
}

// ---------------------------------------------------------------- final edge MLP
// Fused final BN+ReLU (reads L4 conv-out fp16 + AB directly; removes norm16h)

__global__ __launch_bounds__(256) void k_edge_bn(const uint4* __restrict__ X,
                                                 const float* __restrict__ AB,
                                                 const int* __restrict__ src,
                                                 const int* __restrict__ dst,
                                                 const float* __restrict__ fcw,
                                                 const float* __restrict__ fcb,
                                                 float* __restrict__ out) {
    int lane = threadIdx.x & 3;
    size_t t = (size_t)blockIdx.x * 256 + threadIdx.x;
    int eid = (int)(t >> 2);
    if (eid >= EE) return;
    int f0 = lane * 8;
    float a[8], c[8], w[8];
    #pragma unroll
    for (int k = 0; k < 8; k++) {
        a[k] = AB[f0 + k];
        c[k] = AB[32 + f0 + k];
        w[k] = fcw[f0 + k];
    }
    int s = src[eid], d = dst[eid];
    uint4 av = X[(size_t)s * 4 + lane];
    uint4 bv = X[(size_t)d * 4 + lane];
    const __half2* ap = (const __half2*)&av;
    const __half2* bp2 = (const __half2*)&bv;
    float v = 0.f;
    #pragma unroll
    for (int k = 0; k < 4; k++) {
        float2 fa = __half22float2(ap[k]);
        float2 fb = __half22float2(bp2[k]);
        float xs0 = fmaxf(fa.x * a[2 * k] + c[2 * k], 0.f);
        float xd0 = fmaxf(fb.x * a[2 * k] + c[2 * k], 0.f);
        float xs1 = fmaxf(fa.y * a[2 * k + 1] + c[2 * k + 1], 0.f);
        float xd1 = fmaxf(fb.y * a[2 * k + 1] + c[2 * k + 1], 0.f);
        v += xs0 * xd0 * w[2 * k] + xs1 * xd1 * w[2 * k + 1];
    }
    v += __shfl_xor(v, 1, 4);
    v += __shfl_xor(v, 2, 4);
    if (lane == 0) out[eid] = 1.f / (1.f + expf(-(v + fcb[0])));
}

// ---------------------------------------------------------------- launch

extern "C" void kernel_launch(void* const* d_in, const int* in_sizes, int n_in,
                              void* d_out, int out_size, void* d_ws, size_t ws_size,
                              hipStream_t stream) {
    const float* x0 = (const float*)d_in[0];
    const int* ei   = (const int*)d_in[1];
    const int* srcv = ei;
    const int* dstv = ei + EE;
    const float *W[5], *bp[5], *gp[5], *bep[5];
    int idx = 2;
    for (int l = 0; l < 5; l++) {
        W[l]   = (const float*)d_in[idx++];
        bp[l]  = (const float*)d_in[idx++];
        gp[l]  = (const float*)d_in[idx++];
        bep[l] = (const float*)d_in[idx++];
    }
    const float* fcw = (const float*)d_in[22];
    const float* fcb = (const float*)d_in[23];

    char* ws = (char*)d_ws;
    size_t off = 0;
    auto alloc = [&](size_t bytes) -> void* {
        void* p = ws + off;
        off = (off + bytes + 255) & ~(size_t)255;
        return p;
    };
    __half*   conv16  = (__half*)  alloc((size_t)NN * 256 * 2);   // fp16 conv-out
    __half*   act16   = (__half*)  alloc((size_t)NN * 256 * 2);
    __half*   Hh      = (__half*)  alloc((size_t)NN * 128 * 2);
    unsigned* barr    = (unsigned*)alloc((size_t)NB * BCAP * 4);
    int*      colv    = (int*)     alloc((size_t)EE * 4);
    int*      rowptr  = (int*)     alloc((size_t)NN * 4);
    int*      degcnt  = (int*)     alloc((size_t)NN * 4);
    float*    dis     = (float*)   alloc((size_t)NN * 4);
    int*      bcur    = (int*)     alloc((size_t)NB * 4);
    int*      scnblk  = (int*)     alloc(4096);
    float*    part    = (float*)   alloc((size_t)6250 * 256 * 4); // 6.4MB partials
    float*    pmid    = (float*)   alloc((size_t)128 * 512 * 4);  // 256KB mid rows
    float*    bnAB    = (float*)   alloc(512 * 4);
    __half*   Wp      = (__half*)  alloc((size_t)92160 * 2);
    float*    scq     = (float*)   alloc((size_t)NN * 16 * 4);
    const int woff[5] = {0, 16384, 49152, 81920, 90112};

    // q8 rows live in barr's region (dead after CSR build): NN*128 B = 12.8MB
    unsigned char* q8 = (unsigned char*)barr;

    // ---- CSR build (binned counting sort)
    hipMemsetAsync(bcur, 0, (size_t)NB * 4, stream);
    k_bscat<<<(EE + 4095) / 4096, 256, 0, stream>>>(srcv, dstv, bcur, barr);
    k_bdeg<<<NB, 1024, 0, stream>>>(bcur, barr, degcnt, dis);
    int nScanBlk = (NN + 1023) / 1024;
    k_scan_block<<<nScanBlk, 1024, 0, stream>>>(degcnt, rowptr, scnblk, NN);
    k_scan_top<<<1, 64, 0, stream>>>(scnblk, nScanBlk);
    k_scan_add<<<nScanBlk, 1024, 0, stream>>>(rowptr, scnblk, NN);
    k_place<<<NB, 1024, 0, stream>>>(bcur, barr, rowptr, colv);

    // ---- weight packs
    k_wpack_all<<<(92160 + 255) / 256, 256, 0, stream>>>(W[0], W[1], W[2], W[3], W[4], Wp);

    int gx = (NN + 127) / 128;

    // two-stage BN reduce helper counts
    const int P0 = (NN + 31) / 32;   // 3125 (L0, L1, L3)
    const int P2 = (NN + 15) / 16;   // 6250 (L2)
    const int P4 = (NN + 63) / 64;   // 1563 (L4)

    // ---- layer 0: mgemm(AF32: x0)->Hh ; q8p8 ; agg_q8s(+b0,fused BN)->conv16 ; bnmid+fin ; nscale_q8
    {
        dim3 grid(gx, 128 / 64);
        k_mgemm<4, true, false, false, false, true><<<grid, 256, 0, stream>>>(
            x0, Wp + woff[0], Hh, NN, 128, 128, dis, nullptr, nullptr);
        k_q8p8<<<NN * 16 / 256, 256, 0, stream>>>((const uint4*)Hh, (uint2*)q8, scq, NN * 16);
        k_agg_q8s<<<P0, 256, 0, stream>>>(
            (const uint4*)q8, scq, conv16, rowptr, degcnt, colv, dis, bp[0], part);
        int m0 = (P0 + 63) / 64;
        k_bnmid<128><<<m0, 256, 0, stream>>>(part, P0, pmid);
        k_bnfinP<128><<<1, 1024, 0, stream>>>(pmid, m0, gp[0], bep[0], bnAB);
        k_nscale_q8<<<(NN * 16 + 255) / 256, 256, 0, stream>>>(conv16, bnAB, dis, (uint2*)q8, scq);
    }
    // ---- layer 1 (agg first): agg_q8u->act16 ; mgemm(+b1, fp16 out)->conv16 ; bnpart_h ; bnmid+fin
    {
        k_agg_q8u<<<P0, 256, 0, stream>>>(
            (const uint4*)q8, scq, act16, rowptr, degcnt, colv, dis);
        dim3 grid(gx, 256 / 64);
        k_mgemm<4, false, false, false, true, false><<<grid, 256, 0, stream>>>(
            act16, Wp + woff[1], conv16, NN, 128, 256, nullptr, bp[1], nullptr);
        k_bnpart_h<256><<<BNBLK, 256, 0, stream>>>((const uint4*)conv16, part);
        int m1 = (BNBLK + 63) / 64;
        k_bnmid<256><<<m1, 256, 0, stream>>>(part, BNBLK, pmid);
        k_bnfinP<256><<<1, 1024, 0, stream>>>(pmid, m1, gp[1], bep[1], bnAB);
    }
    // ---- layer 2: mgemm(ABN16 d=256)->Hh ; agg_hf<16>(+b2,fused)->conv16 ; bnmid+fin
    {
        dim3 grid(gx, 128 / 64);
        k_mgemm<4, true, true, true, false, false><<<grid, 256, 0, stream>>>(
            conv16, Wp + woff[2], Hh, NN, 256, 128, dis, nullptr, bnAB);
        k_agg_hf<16><<<P2, 256, 0, stream>>>(
            (const uint4*)Hh, conv16, rowptr, degcnt, colv, dis, bp[2], part);
        int m2 = (P2 + 63) / 64;
        k_bnmid<128><<<m2, 256, 0, stream>>>(part, P2, pmid);
        k_bnfinP<128><<<1, 1024, 0, stream>>>(pmid, m2, gp[2], bep[2], bnAB);
    }
    // ---- layer 3 (d=64): mgemm(ABN16 d=128)->Hh ; agg_hf<8>(+b3,fused)->conv16 ; bnmid+fin
    {
        dim3 grid(gx, 64 / 64);
        k_mgemm<4, true, true, true, false, false><<<grid, 256, 0, stream>>>(
            conv16, Wp + woff[3], Hh, NN, 128, 64, dis, nullptr, bnAB);
        k_agg_hf<8><<<P0, 256, 0, stream>>>(
            (const uint4*)Hh, conv16, rowptr, degcnt, colv, dis, bp[3], part);
        int m3 = (P0 + 63) / 64;
        k_bnmid<64><<<m3, 256, 0, stream>>>(part, P0, pmid);
        k_bnfinP<64><<<1, 1024, 0, stream>>>(pmid, m3, gp[3], bep[3], bnAB);
    }
    // ---- layer 4 (d=32): mgemm(ABN16 d=64)->Hh ; agg_hf<4>(+b4,fused)->conv16 ; bnmid+fin
    {
        dim3 grid(gx, 1);
        k_mgemm<2, true, true, true, false, false><<<grid, 256, 0, stream>>>(
            conv16, Wp + woff[4], Hh, NN, 64, 32, dis, nullptr, bnAB);
        k_agg_hf<4><<<P4, 256, 0, stream>>>(
            (const uint4*)Hh, conv16, rowptr, degcnt, colv, dis, bp[4], part);
        int m4 = (P4 + 63) / 64;
        k_bnmid<32><<<m4, 256, 0, stream>>>(part, P4, pmid);
        k_bnfinP<32><<<1, 1024, 0, stream>>>(pmid, m4, gp[4], bep[4], bnAB);
    }

    // ---- edge MLP with fused final BN+ReLU (reads conv16 + bnAB directly)
    size_t edgeThreads = (size_t)EE * 4;
    k_edge_bn<<<(unsigned)((edgeThreads + 255) / 256), 256, 0, stream>>>(
        (const uint4*)conv16, bnAB, srcv, dstv, fcw, fcb, (float*)d_out);
}